// Round 7
// baseline (758.942 us; speedup 1.0000x reference)
//
#include <hip/hip_runtime.h>
#include <hip/hip_bf16.h>

// ---------- types & helpers ----------
typedef __attribute__((ext_vector_type(4))) float f32x4;
typedef __attribute__((ext_vector_type(8))) short s16x8;

__device__ __forceinline__ unsigned short f2bf(float f) {
    __hip_bfloat16 h = __float2bfloat16(f);
    return __builtin_bit_cast(unsigned short, h);
}
__device__ __forceinline__ float bf2f(unsigned short u) {
    return __builtin_bit_cast(float, ((unsigned)u) << 16);
}
__device__ __forceinline__ float2 bfpair(unsigned u) {
    float2 r;
    r.x = __builtin_bit_cast(float, u << 16);
    r.y = __builtin_bit_cast(float, u & 0xffff0000u);
    return r;
}
__device__ __forceinline__ void gload_lds16(const void* g, void* l) {
    __builtin_amdgcn_global_load_lds(
        (const __attribute__((address_space(1))) void*)g,
        (__attribute__((address_space(3))) void*)l, 16, 0, 0);
}

// ---------- convert fp32 -> bf16, 8 elems/thread, exact grid ----------
__global__ void k_f32_to_bf16(const float* __restrict__ in, unsigned short* __restrict__ out) {
    const long i = (long)blockIdx.x * 256 + threadIdx.x;
    const float4 a = ((const float4*)in)[i * 2];
    const float4 b = ((const float4*)in)[i * 2 + 1];
    union { unsigned short h[8]; uint4 u; } r;
    r.h[0] = f2bf(a.x); r.h[1] = f2bf(a.y); r.h[2] = f2bf(a.z); r.h[3] = f2bf(a.w);
    r.h[4] = f2bf(b.x); r.h[5] = f2bf(b.y); r.h[6] = f2bf(b.z); r.h[7] = f2bf(b.w);
    ((uint4*)out)[i] = r.u;
}

// ---------- build [WqT; WkT; WvT] bf16 [1536][512] via LDS 32x32 transpose ----------
__global__ __launch_bounds__(256)
void k_build_wcat(const float* __restrict__ Wq, const float* __restrict__ Wk,
                  const float* __restrict__ Wv, unsigned short* __restrict__ WcatT) {
    __shared__ float t[32][33];
    const int k0 = blockIdx.x * 32;
    const int j0 = blockIdx.y * 32;
    const float* src = (j0 < 512) ? Wq : (j0 < 1024 ? Wk : Wv);
    const int jc0 = j0 & 511;
    const int r = threadIdx.x >> 5, c = threadIdx.x & 31;
#pragma unroll
    for (int rr = 0; rr < 4; ++rr) {
        const int k = k0 + r + rr * 8;
        t[c][r + rr * 8] = src[(long)k * 512 + jc0 + c];
    }
    __syncthreads();
#pragma unroll
    for (int rr = 0; rr < 4; ++rr) {
        const int j = j0 + r + rr * 8;
        WcatT[(long)j * 512 + k0 + c] = f2bf(t[r + rr * 8][c]);
    }
}

// ---------- MFMA bf16 GEMM 128x128 (m97-style): C[M,N] = A[M,K] * B[N,K]^T ----------
#define BM 128
#define BN 128
#define BK 64

template<int OUT_BF16, int BIAS>
__global__ __launch_bounds__(256, 2)
void gemm_mfma(const unsigned short* __restrict__ A, const unsigned short* __restrict__ B,
               void* __restrict__ C_, const float* __restrict__ bias,
               int lda, int ldb, int ldc, int K, long sA, long sB, long sC) {
    __shared__ __align__(16) unsigned short As[BM * BK];
    __shared__ __align__(16) unsigned short Bs[BN * BK];
    const int tid  = threadIdx.x;
    const int wave = tid >> 6;
    const int lane = tid & 63;
    const int wm = wave >> 1, wn = wave & 1;
    const int bm0 = blockIdx.y * BM;
    const int bn0 = blockIdx.x * BN;
    const long bz = blockIdx.z;
    A += bz * sA;
    B += bz * sB;

    const int l15 = lane & 15;
    const int l4  = lane >> 4;

    f32x4 acc[4][4];
#pragma unroll
    for (int i = 0; i < 4; ++i)
#pragma unroll
        for (int j = 0; j < 4; ++j) acc[i][j] = (f32x4){0.f, 0.f, 0.f, 0.f};

    const int srow    = wave * 8 + (lane >> 3);
    const int schunk0 = lane & 7;
    const int arow_b  = wm * 64 + l15;
    const int brow_b  = wn * 64 + l15;

    const int nk = K / BK;
    for (int kt = 0; kt < nk; ++kt) {
        const int k0 = kt * BK;
#pragma unroll
        for (int i = 0; i < 4; ++i) {
            const int r  = i * 32 + srow;
            const int gc = schunk0 ^ (r & 7);
            gload_lds16(A + (long)(bm0 + r) * lda + (k0 + gc * 8), &As[(i * 32 + wave * 8) * BK]);
            gload_lds16(B + (long)(bn0 + r) * ldb + (k0 + gc * 8), &Bs[(i * 32 + wave * 8) * BK]);
        }
        __syncthreads();
        s16x8 af[4][2], bfr[4][2];
#pragma unroll
        for (int mi = 0; mi < 4; ++mi) {
            const int row = arow_b + mi * 16;
#pragma unroll
            for (int ki = 0; ki < 2; ++ki) {
                const int ch = (ki * 4 + l4) ^ (row & 7);
                af[mi][ki] = *(const s16x8*)&As[row * BK + ch * 8];
            }
        }
#pragma unroll
        for (int ni = 0; ni < 4; ++ni) {
            const int row = brow_b + ni * 16;
#pragma unroll
            for (int ki = 0; ki < 2; ++ki) {
                const int ch = (ki * 4 + l4) ^ (row & 7);
                bfr[ni][ki] = *(const s16x8*)&Bs[row * BK + ch * 8];
            }
        }
#pragma unroll
        for (int ki = 0; ki < 2; ++ki)
#pragma unroll
            for (int mi = 0; mi < 4; ++mi)
#pragma unroll
                for (int ni = 0; ni < 4; ++ni)
                    acc[mi][ni] = __builtin_amdgcn_mfma_f32_16x16x32_bf16(
                        af[mi][ki], bfr[ni][ki], acc[mi][ni], 0, 0, 0);
        __syncthreads();
    }

#pragma unroll
    for (int mi = 0; mi < 4; ++mi) {
        const int row0 = bm0 + wm * 64 + mi * 16 + l4 * 4;
#pragma unroll
        for (int ni = 0; ni < 4; ++ni) {
            const int col = bn0 + wn * 64 + ni * 16 + l15;
            if (OUT_BF16) {
                unsigned short* C = (unsigned short*)C_ + bz * sC;
#pragma unroll
                for (int j = 0; j < 4; ++j)
                    C[(long)(row0 + j) * ldc + col] = f2bf(acc[mi][ni][j]);
            } else {
                float* C = (float*)C_ + bz * sC;
                const float bv = BIAS ? bias[col] : 0.f;
#pragma unroll
                for (int j = 0; j < 4; ++j)
                    C[(long)(row0 + j) * ldc + col] = acc[mi][ni][j] + bv;
            }
        }
    }
}

// ---------- G partials: P[b][chunk][tr*4+tc][128][128] = sum_{n in chunk} X[n,ci]*X[n,cj] ----------
// X staged transposed in LDS ([chan][token], XOR-swizzled) -- attn_mfma-verified pattern.
__global__ __launch_bounds__(256)
void k_xtx(const unsigned short* __restrict__ X, float* __restrict__ P) {
    __shared__ __align__(16) unsigned short XTI[128 * 64];
    __shared__ __align__(16) unsigned short XTJ[128 * 64];
    const int t = threadIdx.x, wave = t >> 6, lane = t & 63;
    const int l15 = lane & 15, l4 = lane >> 4;
    const int tp = blockIdx.x, chunk = blockIdx.y, b = blockIdx.z;
    const int ti = tp >> 2, tj = tp & 3;
    const int ci0 = ti * 128, cj0 = tj * 128;
    const bool diag = (ti == tj);

    f32x4 acc[2][8];
#pragma unroll
    for (int i = 0; i < 2; ++i)
#pragma unroll
        for (int j = 0; j < 8; ++j) acc[i][j] = (f32x4){0.f, 0.f, 0.f, 0.f};

    const int c0  = (t & 63) * 2;           // chan pair within tile
    const int rg  = (t >> 6) * 16;          // token group base
    const int swz = ((c0 >> 1) & 7) * 8;
    const long tokbase = (long)b * 16384 + chunk * 2048;

    for (int step = 0; step < 32; ++step) {
        __syncthreads();
        const long rowbase = tokbase + step * 64;
#pragma unroll
        for (int i = 0; i < 16; ++i) {
            const int r  = rg + i;
            const int xr = r ^ swz;
            const long g = (rowbase + r) * 512;
            const unsigned ui = *(const unsigned*)(X + g + ci0 + c0);
            XTI[c0 * 64 + xr]       = (unsigned short)(ui & 0xffff);
            XTI[(c0 + 1) * 64 + xr] = (unsigned short)(ui >> 16);
            if (!diag) {
                const unsigned uj = *(const unsigned*)(X + g + cj0 + c0);
                XTJ[c0 * 64 + xr]       = (unsigned short)(uj & 0xffff);
                XTJ[(c0 + 1) * 64 + xr] = (unsigned short)(uj >> 16);
            }
        }
        __syncthreads();
        const unsigned short* BT = diag ? XTI : XTJ;
        s16x8 af[2][2];
#pragma unroll
        for (int mi = 0; mi < 2; ++mi) {
            const int arow = wave * 32 + mi * 16 + l15;
            const int aswz = (arow >> 1) & 7;
            af[mi][0] = *(const s16x8*)&XTI[arow * 64 + ((l4) ^ aswz) * 8];
            af[mi][1] = *(const s16x8*)&XTI[arow * 64 + ((4 + l4) ^ aswz) * 8];
        }
#pragma unroll
        for (int ni = 0; ni < 8; ++ni) {
            const int brow = ni * 16 + l15;
            const int bswz = (brow >> 1) & 7;
            const s16x8 b0 = *(const s16x8*)&BT[brow * 64 + ((l4) ^ bswz) * 8];
            const s16x8 b1 = *(const s16x8*)&BT[brow * 64 + ((4 + l4) ^ bswz) * 8];
            acc[0][ni] = __builtin_amdgcn_mfma_f32_16x16x32_bf16(af[0][0], b0, acc[0][ni], 0, 0, 0);
            acc[0][ni] = __builtin_amdgcn_mfma_f32_16x16x32_bf16(af[0][1], b1, acc[0][ni], 0, 0, 0);
            acc[1][ni] = __builtin_amdgcn_mfma_f32_16x16x32_bf16(af[1][0], b0, acc[1][ni], 0, 0, 0);
            acc[1][ni] = __builtin_amdgcn_mfma_f32_16x16x32_bf16(af[1][1], b1, acc[1][ni], 0, 0, 0);
        }
    }

    float* Pb = P + ((long)((b * 8 + chunk) * 16 + tp)) * 16384;
#pragma unroll
    for (int mi = 0; mi < 2; ++mi) {
        const int row0 = wave * 32 + mi * 16 + l4 * 4;
#pragma unroll
        for (int ni = 0; ni < 8; ++ni) {
            const int col = ni * 16 + l15;
#pragma unroll
            for (int j = 0; j < 4; ++j)
                Pb[(row0 + j) * 128 + col] = acc[mi][ni][j];
        }
    }
}

// ---------- reduce partials over chunks -> GB bf16 [4][512][512] ----------
__global__ void k_greduce(const float* __restrict__ P, unsigned* __restrict__ GB2) {
    const long idx = (long)blockIdx.x * 256 + threadIdx.x;   // 0..524287 (2 elems each)
    const int b   = (int)(idx >> 17);
    const int rem = (int)(idx & 131071);
    const int c   = rem >> 8;
    const int cp0 = (rem & 255) * 2;
    const int tp  = (c >> 7) * 4 + (cp0 >> 7);
    const int e   = (c & 127) * 128 + (cp0 & 127);
    const float* Pp = P + ((long)(b * 8) * 16 + tp) * 16384 + e;
    float s0 = 0.f, s1 = 0.f;
#pragma unroll
    for (int ch = 0; ch < 8; ++ch) {
        const float2 v = *(const float2*)(Pp + (long)ch * 16 * 16384);
        s0 += v.x; s1 += v.y;
    }
    GB2[idx] = (unsigned)f2bf(s0) | ((unsigned)f2bf(s1) << 16);
}

// ---------- row-dots for sumsq: q: WqT.T1e rows; k: WkT.T2e rows ----------
__global__ void k_ssq(const unsigned short* __restrict__ WCT, const unsigned short* __restrict__ T1e,
                      const unsigned short* __restrict__ T2e, float* __restrict__ SSQ) {
    const int b = blockIdx.y;
    const int o = blockIdx.x * 256 + threadIdx.x;   // 0..1023
    const unsigned short* wrow;
    const unsigned short* trow;
    if (o < 512) {
        wrow = WCT + (long)o * 512;
        trow = T1e + (long)b * 262144 + (long)o * 512;
    } else {
        const int d = o - 512;
        wrow = WCT + 262144 + (long)d * 512;
        trow = T2e + (long)b * 262144 + (long)d * 512;
    }
    float s = 0.f;
    for (int c = 0; c < 512; c += 8) {
        const s16x8 w = *(const s16x8*)&wrow[c];
        const s16x8 v = *(const s16x8*)&trow[c];
#pragma unroll
        for (int j = 0; j < 8; ++j)
            s += bf2f((unsigned short)w[j]) * bf2f((unsigned short)v[j]);
    }
    SSQ[b * 1024 + o] = s;
}

// ---------- normalize + softmax over e (reads diag head-blocks of ATTF) ----------
__global__ void k_softmax(float* __restrict__ attn, const float* __restrict__ sumsq,
                          const float* __restrict__ rescale) {
    const int bh = blockIdx.x;
    const int b = bh >> 3, h = bh & 7;
    const int d = threadIdx.x; // 64
    const float rs   = rescale[h];
    const float invk = rsqrtf(sumsq[b * 1024 + 512 + h * 64 + d]);
    __shared__ float invq[64];
    invq[d] = rsqrtf(sumsq[b * 1024 + h * 64 + d]);
    __syncthreads();
    float* row = attn + ((long)b * 512 + h * 64 + d) * 512 + h * 64;
    float mx = -1e30f;
#pragma unroll
    for (int e = 0; e < 64; ++e) mx = fmaxf(mx, row[e] * invk * invq[e] * rs);
    float s = 0.f;
#pragma unroll
    for (int e = 0; e < 64; ++e) {
        const float l = expf(row[e] * invk * invq[e] * rs - mx);
        row[e] = l;
        s += l;
    }
    const float inv = 1.f / s;
#pragma unroll
    for (int e = 0; e < 64; ++e) row[e] *= inv;
}

// ---------- Weff^T[b][cout][h*64+e] = sum_d attn[b,h,d,e] * Wp[h*64+d][cout] ----------
__global__ __launch_bounds__(256)
void k_weff(const float* __restrict__ attn, const float* __restrict__ Wp,
            unsigned short* __restrict__ WeffT) {
    const int h = blockIdx.x, b = blockIdx.y;
    __shared__ float At[64 * 64];   // [d][e]
    __shared__ float Wt[64 * 128];  // [d][c]
    const int t = threadIdx.x;
    const float* arow = attn + ((long)b * 512 + h * 64) * 512 + h * 64;
    for (int i = 0; i < 16; ++i) {
        const int idx = i * 256 + t;
        const int d = idx >> 6, e = idx & 63;
        At[idx] = arow[(long)d * 512 + e];
    }
    const int e = t & 63, cs = t >> 6;
    for (int cc = 0; cc < 512; cc += 128) {
        __syncthreads();
        for (int i = 0; i < 32; ++i) {
            const int idx = i * 256 + t;
            const int d = idx >> 7, c = idx & 127;
            Wt[idx] = Wp[(long)(h * 64 + d) * 512 + cc + c];
        }
        __syncthreads();
        for (int i = 0; i < 32; ++i) {
            const int cl = cs * 32 + i;
            float acc = 0.f;
#pragma unroll
            for (int d = 0; d < 64; ++d) acc += At[d * 64 + e] * Wt[d * 128 + cl];
            WeffT[((long)b * 512 + cc + cl) * 512 + h * 64 + e] = f2bf(acc);
        }
    }
}

// ---------- depthwise 3x3 conv, x-chunked ----------
__global__ __launch_bounds__(256)
void k_conv1_gelu(const unsigned short* __restrict__ V,   // pixel stride 512
                  const float* __restrict__ w, unsigned short* __restrict__ g) {
    const int x0 = blockIdx.x * 16;
    const int y  = blockIdx.y;
    const int b  = blockIdx.z;
    const int c0 = threadIdx.x * 2;
    float wq0[9], wq1[9];
#pragma unroll
    for (int i = 0; i < 9; ++i) { wq0[i] = w[c0 * 9 + i]; wq1[i] = w[(c0 + 1) * 9 + i]; }
    const long pixbase = (long)b * 16384;

    auto ld = [&](int yy, int xx) -> float2 {
        if (yy < 0 || yy > 127 || xx < 0 || xx > 127) return make_float2(0.f, 0.f);
        return bfpair(*(const unsigned*)(V + (pixbase + (long)yy * 128 + xx) * 512 + c0));
    };

    float2 win[3][3];
#pragma unroll
    for (int ky = 0; ky < 3; ++ky) {
        win[ky][0] = ld(y + ky - 1, x0 - 1);
        win[ky][1] = ld(y + ky - 1, x0);
    }
    for (int xi = 0; xi < 16; ++xi) {
        const int x = x0 + xi;
#pragma unroll
        for (int ky = 0; ky < 3; ++ky) win[ky][2] = ld(y + ky - 1, x + 1);
        float a0 = 0.f, a1 = 0.f;
#pragma unroll
        for (int ky = 0; ky < 3; ++ky)
#pragma unroll
            for (int kx = 0; kx < 3; ++kx) {
                a0 += win[ky][kx].x * wq0[ky * 3 + kx];
                a1 += win[ky][kx].y * wq1[ky * 3 + kx];
            }
        a0 = 0.5f * a0 * (1.f + erff(a0 * 0.70710678118654752f));
        a1 = 0.5f * a1 * (1.f + erff(a1 * 0.70710678118654752f));
        const unsigned up = (unsigned)f2bf(a0) | ((unsigned)f2bf(a1) << 16);
        *(unsigned*)(g + (pixbase + (long)y * 128 + x) * 512 + c0) = up;
#pragma unroll
        for (int ky = 0; ky < 3; ++ky) {
            win[ky][0] = win[ky][1];
            win[ky][1] = win[ky][2];
        }
    }
}

__global__ __launch_bounds__(256)
void k_conv2_add(const unsigned short* __restrict__ gin,
                 const float* __restrict__ w, float* __restrict__ out) {
    const int x0 = blockIdx.x * 16;
    const int y  = blockIdx.y;
    const int b  = blockIdx.z;
    const int c0 = threadIdx.x * 2;
    float wq0[9], wq1[9];
#pragma unroll
    for (int i = 0; i < 9; ++i) { wq0[i] = w[c0 * 9 + i]; wq1[i] = w[(c0 + 1) * 9 + i]; }
    const long pixbase = (long)b * 16384;

    auto ld = [&](int yy, int xx) -> float2 {
        if (yy < 0 || yy > 127 || xx < 0 || xx > 127) return make_float2(0.f, 0.f);
        return bfpair(*(const unsigned*)(gin + (pixbase + (long)yy * 128 + xx) * 512 + c0));
    };

    float2 win[3][3];
#pragma unroll
    for (int ky = 0; ky < 3; ++ky) {
        win[ky][0] = ld(y + ky - 1, x0 - 1);
        win[ky][1] = ld(y + ky - 1, x0);
    }
    for (int xi = 0; xi < 16; ++xi) {
        const int x = x0 + xi;
#pragma unroll
        for (int ky = 0; ky < 3; ++ky) win[ky][2] = ld(y + ky - 1, x + 1);
        float a0 = 0.f, a1 = 0.f;
#pragma unroll
        for (int ky = 0; ky < 3; ++ky)
#pragma unroll
            for (int kx = 0; kx < 3; ++kx) {
                a0 += win[ky][kx].x * wq0[ky * 3 + kx];
                a1 += win[ky][kx].y * wq1[ky * 3 + kx];
            }
        float2* o = (float2*)(out + (pixbase + (long)y * 128 + x) * 512 + c0);
        float2 p = *o;
        p.x += a0; p.y += a1;
        *o = p;
#pragma unroll
        for (int ky = 0; ky < 3; ++ky) {
            win[ky][0] = win[ky][1];
            win[ky][1] = win[ky][2];
        }
    }
}

// ---------- launch ----------
extern "C" void kernel_launch(void* const* d_in, const int* in_sizes, int n_in,
                              void* d_out, int out_size, void* d_ws, size_t ws_size,
                              hipStream_t stream) {
    const float* x_in    = (const float*)d_in[0];
    const float* Wq      = (const float*)d_in[1];
    const float* Wk      = (const float*)d_in[2];
    const float* Wv      = (const float*)d_in[3];
    const float* rescale = (const float*)d_in[4];
    const float* Wp      = (const float*)d_in[5];
    const float* bp      = (const float*)d_in[6];
    const float* c1w     = (const float*)d_in[7];
    const float* c2w     = (const float*)d_in[8];
    float* out = (float*)d_out;

    char* ws = (char*)d_ws;
    unsigned short* XBF = (unsigned short*)(ws);                  // [65536][512] bf16; reused as gelu buf
    unsigned short* VBF = (unsigned short*)(ws + 67108864LL);     // [65536][512] bf16
    float*          P   = (float*)(ws + 134217728LL);             // [4][8][16][16384] f32 partials
    unsigned short* WCT = (unsigned short*)(ws + 167772160LL);    // [WqT;WkT;WvT] [1536][512] bf16
    unsigned short* GB  = (unsigned short*)(ws + 169345024LL);    // [4][512][512] bf16
    unsigned short* T1e = (unsigned short*)(ws + 171442176LL);    // Wq^T G  [4][512][512] bf16
    unsigned short* T2e = (unsigned short*)(ws + 173539328LL);    // Wk^T G  [4][512][512] bf16
    float*          SSQ = (float*)(ws + 175636480LL);             // [4][1024]
    float*          ATTF= (float*)(ws + 175652864LL);             // [4][512][512] f32
    unsigned short* WEF = (unsigned short*)(ws + 179847168LL);    // WeffT [4][512][512] bf16

    k_f32_to_bf16<<<dim3(16384), dim3(256), 0, stream>>>(x_in, XBF);
    k_build_wcat<<<dim3(16, 48), dim3(256), 0, stream>>>(Wq, Wk, Wv, WCT);

    // V = X @ Wv  (M=65536, N=512, K=512)
    gemm_mfma<1, 0><<<dim3(4, 512, 1), dim3(256), 0, stream>>>(
        XBF, WCT + 2 * 262144, (void*)VBF, nullptr, 512, 512, 512, 512, 0L, 0L, 0L);

    // Gram matrix G = X^T X per batch (chunked partials, then reduce -> bf16)
    k_xtx<<<dim3(16, 8, 4), dim3(256), 0, stream>>>(XBF, P);
    k_greduce<<<dim3(2048), dim3(256), 0, stream>>>(P, (unsigned*)GB);

    // sandwiches: T2e = WkT*GB^T, T1e = WqT*GB^T, attn = T2e*WqT^T (fp32 out)
    gemm_mfma<1, 0><<<dim3(4, 4, 4), dim3(256), 0, stream>>>(
        WCT + 262144, GB, (void*)T2e, nullptr, 512, 512, 512, 512, 0L, 262144L, 262144L);
    gemm_mfma<1, 0><<<dim3(4, 4, 4), dim3(256), 0, stream>>>(
        WCT, GB, (void*)T1e, nullptr, 512, 512, 512, 512, 0L, 262144L, 262144L);
    gemm_mfma<0, 0><<<dim3(4, 4, 4), dim3(256), 0, stream>>>(
        T2e, WCT, (void*)ATTF, nullptr, 512, 512, 512, 512, 262144L, 0L, 262144L);

    k_ssq<<<dim3(4, 4), dim3(256), 0, stream>>>(WCT, T1e, T2e, SSQ);
    k_softmax<<<dim3(32), dim3(64), 0, stream>>>(ATTF, SSQ, rescale);
    k_weff<<<dim3(8, 4), dim3(256), 0, stream>>>(ATTF, Wp, WEF);

    // out_c = V @ Weff^T + bp  (batched: M=16384, N=512, K=512)
    gemm_mfma<0, 1><<<dim3(4, 128, 4), dim3(256), 0, stream>>>(
        VBF, WEF, (void*)out, bp, 512, 512, 512, 512,
        (long)16384 * 512, 262144L, (long)16384 * 512);

    // positional branch: dwconv3x3 -> gelu -> dwconv3x3, += into out
    k_conv1_gelu<<<dim3(8, 128, 4), dim3(256), 0, stream>>>(VBF, c1w, XBF);
    k_conv2_add<<<dim3(8, 128, 4), dim3(256), 0, stream>>>(XBF, c2w, out);
}

// Round 8
// 531.283 us; speedup vs baseline: 1.4285x; 1.4285x over previous
//
#include <hip/hip_runtime.h>
#include <hip/hip_bf16.h>

// ---------- types & helpers ----------
typedef __attribute__((ext_vector_type(4))) float f32x4;
typedef __attribute__((ext_vector_type(8))) short s16x8;

__device__ __forceinline__ unsigned short f2bf(float f) {
    __hip_bfloat16 h = __float2bfloat16(f);
    return __builtin_bit_cast(unsigned short, h);
}
__device__ __forceinline__ float bf2f(unsigned short u) {
    return __builtin_bit_cast(float, ((unsigned)u) << 16);
}
__device__ __forceinline__ float2 bfpair(unsigned u) {
    float2 r;
    r.x = __builtin_bit_cast(float, u << 16);
    r.y = __builtin_bit_cast(float, u & 0xffff0000u);
    return r;
}
__device__ __forceinline__ void gload_lds16(const void* g, void* l) {
    __builtin_amdgcn_global_load_lds(
        (const __attribute__((address_space(1))) void*)g,
        (__attribute__((address_space(3))) void*)l, 16, 0, 0);
}

// ---------- fused fp32->bf16 convert + transpose ----------
// Writes XBF [65536][512] (row-major) and XT [4][512][16384] (chan-major).
// LDS tile 64x64 with chunk-XOR swizzle: elem (c,tok) at c*64 + ((tok>>3)^(c&7))*8 + (tok&7).
__global__ __launch_bounds__(256)
void k_cvt_tr(const float* __restrict__ in, unsigned short* __restrict__ XBF,
              unsigned short* __restrict__ XT) {
    __shared__ __align__(16) unsigned short tile[64 * 64];
    const int t  = threadIdx.x;
    const int c0 = blockIdx.x * 64;           // chan tile base
    const int ty = blockIdx.y;                // token tile (global)
    const long tokg = (long)ty * 64;
    const int cq = t & 15, r0 = t >> 4;
#pragma unroll
    for (int p = 0; p < 4; ++p) {
        const int tok = r0 + p * 16;
        const float4 v = *(const float4*)(in + (tokg + tok) * 512 + c0 + cq * 4);
        union { unsigned short h[4]; uint2 u; } pk;
        pk.h[0] = f2bf(v.x); pk.h[1] = f2bf(v.y); pk.h[2] = f2bf(v.z); pk.h[3] = f2bf(v.w);
        *(uint2*)(XBF + (tokg + tok) * 512 + c0 + cq * 4) = pk.u;   // straight write
        const int T = tok >> 3, i = tok & 7;
#pragma unroll
        for (int j = 0; j < 4; ++j) {
            const int c = cq * 4 + j;
            tile[c * 64 + ((T ^ (c & 7)) * 8 + i)] = pk.h[j];
        }
    }
    __syncthreads();
    const int b  = ty >> 8;                    // 256 token tiles per batch
    const long tb = (long)(ty & 255) * 64;     // token base within batch
    const int T2 = t & 7;
#pragma unroll
    for (int q = 0; q < 2; ++q) {
        const int c = (t >> 3) + q * 32;
        const uint4 v = *(const uint4*)&tile[c * 64 + ((T2 ^ (c & 7)) * 8)];
        *(uint4*)(XT + ((long)(b * 512 + c0 + c)) * 16384 + tb + T2 * 8) = v;
    }
}

// ---------- build [WqT; WkT; WvT] bf16 [1536][512] via LDS 32x32 transpose ----------
__global__ __launch_bounds__(256)
void k_build_wcat(const float* __restrict__ Wq, const float* __restrict__ Wk,
                  const float* __restrict__ Wv, unsigned short* __restrict__ WcatT) {
    __shared__ float t[32][33];
    const int k0 = blockIdx.x * 32;
    const int j0 = blockIdx.y * 32;
    const float* src = (j0 < 512) ? Wq : (j0 < 1024 ? Wk : Wv);
    const int jc0 = j0 & 511;
    const int r = threadIdx.x >> 5, c = threadIdx.x & 31;
#pragma unroll
    for (int rr = 0; rr < 4; ++rr) {
        const int k = k0 + r + rr * 8;
        t[c][r + rr * 8] = src[(long)k * 512 + jc0 + c];
    }
    __syncthreads();
#pragma unroll
    for (int rr = 0; rr < 4; ++rr) {
        const int j = j0 + r + rr * 8;
        WcatT[(long)j * 512 + k0 + c] = f2bf(t[r + rr * 8][c]);
    }
}

// ---------- MFMA bf16 GEMM 128x128 (m97-style): C[M,N] = A[M,K] * B[N,K]^T ----------
#define BM 128
#define BN 128
#define BK 64

template<int OUT_BF16, int BIAS>
__global__ __launch_bounds__(256, 2)
void gemm_mfma(const unsigned short* __restrict__ A, const unsigned short* __restrict__ B,
               void* __restrict__ C_, const float* __restrict__ bias,
               int lda, int ldb, int ldc, int K, long sA, long sB, long sC) {
    __shared__ __align__(16) unsigned short As[BM * BK];
    __shared__ __align__(16) unsigned short Bs[BN * BK];
    const int tid  = threadIdx.x;
    const int wave = tid >> 6;
    const int lane = tid & 63;
    const int wm = wave >> 1, wn = wave & 1;
    const int bm0 = blockIdx.y * BM;
    const int bn0 = blockIdx.x * BN;
    const long bz = blockIdx.z;
    A += bz * sA;
    B += bz * sB;

    const int l15 = lane & 15;
    const int l4  = lane >> 4;

    f32x4 acc[4][4];
#pragma unroll
    for (int i = 0; i < 4; ++i)
#pragma unroll
        for (int j = 0; j < 4; ++j) acc[i][j] = (f32x4){0.f, 0.f, 0.f, 0.f};

    const int srow    = wave * 8 + (lane >> 3);
    const int schunk0 = lane & 7;
    const int arow_b  = wm * 64 + l15;
    const int brow_b  = wn * 64 + l15;

    const int nk = K / BK;
    for (int kt = 0; kt < nk; ++kt) {
        const int k0 = kt * BK;
#pragma unroll
        for (int i = 0; i < 4; ++i) {
            const int r  = i * 32 + srow;
            const int gc = schunk0 ^ (r & 7);
            gload_lds16(A + (long)(bm0 + r) * lda + (k0 + gc * 8), &As[(i * 32 + wave * 8) * BK]);
            gload_lds16(B + (long)(bn0 + r) * ldb + (k0 + gc * 8), &Bs[(i * 32 + wave * 8) * BK]);
        }
        __syncthreads();
        s16x8 af[4][2], bfr[4][2];
#pragma unroll
        for (int mi = 0; mi < 4; ++mi) {
            const int row = arow_b + mi * 16;
#pragma unroll
            for (int ki = 0; ki < 2; ++ki) {
                const int ch = (ki * 4 + l4) ^ (row & 7);
                af[mi][ki] = *(const s16x8*)&As[row * BK + ch * 8];
            }
        }
#pragma unroll
        for (int ni = 0; ni < 4; ++ni) {
            const int row = brow_b + ni * 16;
#pragma unroll
            for (int ki = 0; ki < 2; ++ki) {
                const int ch = (ki * 4 + l4) ^ (row & 7);
                bfr[ni][ki] = *(const s16x8*)&Bs[row * BK + ch * 8];
            }
        }
#pragma unroll
        for (int ki = 0; ki < 2; ++ki)
#pragma unroll
            for (int mi = 0; mi < 4; ++mi)
#pragma unroll
                for (int ni = 0; ni < 4; ++ni)
                    acc[mi][ni] = __builtin_amdgcn_mfma_f32_16x16x32_bf16(
                        af[mi][ki], bfr[ni][ki], acc[mi][ni], 0, 0, 0);
        __syncthreads();
    }

#pragma unroll
    for (int mi = 0; mi < 4; ++mi) {
        const int row0 = bm0 + wm * 64 + mi * 16 + l4 * 4;
#pragma unroll
        for (int ni = 0; ni < 4; ++ni) {
            const int col = bn0 + wn * 64 + ni * 16 + l15;
            if (OUT_BF16) {
                unsigned short* C = (unsigned short*)C_ + bz * sC;
#pragma unroll
                for (int j = 0; j < 4; ++j)
                    C[(long)(row0 + j) * ldc + col] = f2bf(acc[mi][ni][j]);
            } else {
                float* C = (float*)C_ + bz * sC;
                const float bv = BIAS ? bias[col] : 0.f;
#pragma unroll
                for (int j = 0; j < 4; ++j)
                    C[(long)(row0 + j) * ldc + col] = acc[mi][ni][j] + bv;
            }
        }
    }
}

// ---------- Gram split-K: P[(b*8+chunk)*16 + ti*4+tj] = XT_tile_i . XT_tile_j^T over 2048 tokens ----------
__global__ __launch_bounds__(256, 2)
void gemm_gram(const unsigned short* __restrict__ XT, float* __restrict__ P) {
    __shared__ __align__(16) unsigned short As[128 * 64];
    __shared__ __align__(16) unsigned short Bs[128 * 64];
    const int tid = threadIdx.x, wave = tid >> 6, lane = tid & 63;
    const int wm = wave >> 1, wn = wave & 1;
    const int bm0 = blockIdx.y * 128, bn0 = blockIdx.x * 128;
    const int z = blockIdx.z, b = z >> 3, chunk = z & 7;
    const unsigned short* A = XT + (long)b * 512 * 16384;
    const int l15 = lane & 15, l4 = lane >> 4;

    f32x4 acc[4][4];
#pragma unroll
    for (int i = 0; i < 4; ++i)
#pragma unroll
        for (int j = 0; j < 4; ++j) acc[i][j] = (f32x4){0.f, 0.f, 0.f, 0.f};

    const int srow = wave * 8 + (lane >> 3);
    const int sch  = lane & 7;
    const int arow_b = wm * 64 + l15;
    const int brow_b = wn * 64 + l15;

    for (int kt = 0; kt < 32; ++kt) {
        const long k0 = (long)chunk * 2048 + kt * 64;
#pragma unroll
        for (int i = 0; i < 4; ++i) {
            const int r  = i * 32 + srow;
            const int gc = sch ^ (r & 7);
            gload_lds16(A + (long)(bm0 + r) * 16384 + k0 + gc * 8, &As[(i * 32 + wave * 8) * 64]);
            gload_lds16(A + (long)(bn0 + r) * 16384 + k0 + gc * 8, &Bs[(i * 32 + wave * 8) * 64]);
        }
        __syncthreads();
        s16x8 af[4][2], bfr[4][2];
#pragma unroll
        for (int mi = 0; mi < 4; ++mi) {
            const int row = arow_b + mi * 16;
#pragma unroll
            for (int ki = 0; ki < 2; ++ki)
                af[mi][ki] = *(const s16x8*)&As[row * 64 + (((ki * 4 + l4) ^ (row & 7))) * 8];
        }
#pragma unroll
        for (int ni = 0; ni < 4; ++ni) {
            const int row = brow_b + ni * 16;
#pragma unroll
            for (int ki = 0; ki < 2; ++ki)
                bfr[ni][ki] = *(const s16x8*)&Bs[row * 64 + (((ki * 4 + l4) ^ (row & 7))) * 8];
        }
#pragma unroll
        for (int ki = 0; ki < 2; ++ki)
#pragma unroll
            for (int mi = 0; mi < 4; ++mi)
#pragma unroll
                for (int ni = 0; ni < 4; ++ni)
                    acc[mi][ni] = __builtin_amdgcn_mfma_f32_16x16x32_bf16(
                        af[mi][ki], bfr[ni][ki], acc[mi][ni], 0, 0, 0);
        __syncthreads();
    }

    float* Pb = P + ((long)((b * 8 + chunk) * 16 + blockIdx.y * 4 + blockIdx.x)) * 16384;
#pragma unroll
    for (int mi = 0; mi < 4; ++mi) {
        const int row0 = wm * 64 + mi * 16 + l4 * 4;
#pragma unroll
        for (int ni = 0; ni < 4; ++ni) {
            const int col = wn * 64 + ni * 16 + l15;
#pragma unroll
            for (int j = 0; j < 4; ++j)
                Pb[(row0 + j) * 128 + col] = acc[mi][ni][j];
        }
    }
}

// ---------- reduce partials over chunks -> GB bf16 [4][512][512] ----------
__global__ void k_greduce(const float* __restrict__ P, unsigned* __restrict__ GB2) {
    const long idx = (long)blockIdx.x * 256 + threadIdx.x;   // 0..524287 (2 elems each)
    const int b   = (int)(idx >> 17);
    const int rem = (int)(idx & 131071);
    const int c   = rem >> 8;
    const int cp0 = (rem & 255) * 2;
    const int tp  = (c >> 7) * 4 + (cp0 >> 7);
    const int e   = (c & 127) * 128 + (cp0 & 127);
    const float* Pp = P + ((long)(b * 8) * 16 + tp) * 16384 + e;
    float s0 = 0.f, s1 = 0.f;
#pragma unroll
    for (int ch = 0; ch < 8; ++ch) {
        const float2 v = *(const float2*)(Pp + (long)ch * 16 * 16384);
        s0 += v.x; s1 += v.y;
    }
    GB2[idx] = (unsigned)f2bf(s0) | ((unsigned)f2bf(s1) << 16);
}

// ---------- row-dots for sumsq ----------
__global__ void k_ssq(const unsigned short* __restrict__ WCT, const unsigned short* __restrict__ T1e,
                      const unsigned short* __restrict__ T2e, float* __restrict__ SSQ) {
    const int b = blockIdx.y;
    const int o = blockIdx.x * 256 + threadIdx.x;   // 0..1023
    const unsigned short* wrow;
    const unsigned short* trow;
    if (o < 512) {
        wrow = WCT + (long)o * 512;
        trow = T1e + (long)b * 262144 + (long)o * 512;
    } else {
        const int d = o - 512;
        wrow = WCT + 262144 + (long)d * 512;
        trow = T2e + (long)b * 262144 + (long)d * 512;
    }
    float s = 0.f;
    for (int c = 0; c < 512; c += 8) {
        const s16x8 w = *(const s16x8*)&wrow[c];
        const s16x8 v = *(const s16x8*)&trow[c];
#pragma unroll
        for (int j = 0; j < 8; ++j)
            s += bf2f((unsigned short)w[j]) * bf2f((unsigned short)v[j]);
    }
    SSQ[b * 1024 + o] = s;
}

// ---------- normalize + softmax over e (reads diag head-blocks of ATTF) ----------
__global__ void k_softmax(float* __restrict__ attn, const float* __restrict__ sumsq,
                          const float* __restrict__ rescale) {
    const int bh = blockIdx.x;
    const int b = bh >> 3, h = bh & 7;
    const int d = threadIdx.x; // 64
    const float rs   = rescale[h];
    const float invk = rsqrtf(sumsq[b * 1024 + 512 + h * 64 + d]);
    __shared__ float invq[64];
    invq[d] = rsqrtf(sumsq[b * 1024 + h * 64 + d]);
    __syncthreads();
    float* row = attn + ((long)b * 512 + h * 64 + d) * 512 + h * 64;
    float mx = -1e30f;
#pragma unroll
    for (int e = 0; e < 64; ++e) mx = fmaxf(mx, row[e] * invk * invq[e] * rs);
    float s = 0.f;
#pragma unroll
    for (int e = 0; e < 64; ++e) {
        const float l = expf(row[e] * invk * invq[e] * rs - mx);
        row[e] = l;
        s += l;
    }
    const float inv = 1.f / s;
#pragma unroll
    for (int e = 0; e < 64; ++e) row[e] *= inv;
}

// ---------- Weff^T[b][cout][h*64+e] = sum_d attn[b,h,d,e] * Wp[h*64+d][cout] ----------
__global__ __launch_bounds__(256)
void k_weff(const float* __restrict__ attn, const float* __restrict__ Wp,
            unsigned short* __restrict__ WeffT) {
    const int h = blockIdx.x, b = blockIdx.y;
    __shared__ float At[64 * 64];   // [d][e]
    __shared__ float Wt[64 * 128];  // [d][c]
    const int t = threadIdx.x;
    const float* arow = attn + ((long)b * 512 + h * 64) * 512 + h * 64;
    for (int i = 0; i < 16; ++i) {
        const int idx = i * 256 + t;
        const int d = idx >> 6, e = idx & 63;
        At[idx] = arow[(long)d * 512 + e];
    }
    const int e = t & 63, cs = t >> 6;
    for (int cc = 0; cc < 512; cc += 128) {
        __syncthreads();
        for (int i = 0; i < 32; ++i) {
            const int idx = i * 256 + t;
            const int d = idx >> 7, c = idx & 127;
            Wt[idx] = Wp[(long)(h * 64 + d) * 512 + cc + c];
        }
        __syncthreads();
        for (int i = 0; i < 32; ++i) {
            const int cl = cs * 32 + i;
            float acc = 0.f;
#pragma unroll
            for (int d = 0; d < 64; ++d) acc += At[d * 64 + e] * Wt[d * 128 + cl];
            WeffT[((long)b * 512 + cc + cl) * 512 + h * 64 + e] = f2bf(acc);
        }
    }
}

// ---------- depthwise 3x3 conv, x-chunked ----------
__global__ __launch_bounds__(256)
void k_conv1_gelu(const unsigned short* __restrict__ V,   // pixel stride 512
                  const float* __restrict__ w, unsigned short* __restrict__ g) {
    const int x0 = blockIdx.x * 16;
    const int y  = blockIdx.y;
    const int b  = blockIdx.z;
    const int c0 = threadIdx.x * 2;
    float wq0[9], wq1[9];
#pragma unroll
    for (int i = 0; i < 9; ++i) { wq0[i] = w[c0 * 9 + i]; wq1[i] = w[(c0 + 1) * 9 + i]; }
    const long pixbase = (long)b * 16384;

    auto ld = [&](int yy, int xx) -> float2 {
        if (yy < 0 || yy > 127 || xx < 0 || xx > 127) return make_float2(0.f, 0.f);
        return bfpair(*(const unsigned*)(V + (pixbase + (long)yy * 128 + xx) * 512 + c0));
    };

    float2 win[3][3];
#pragma unroll
    for (int ky = 0; ky < 3; ++ky) {
        win[ky][0] = ld(y + ky - 1, x0 - 1);
        win[ky][1] = ld(y + ky - 1, x0);
    }
    for (int xi = 0; xi < 16; ++xi) {
        const int x = x0 + xi;
#pragma unroll
        for (int ky = 0; ky < 3; ++ky) win[ky][2] = ld(y + ky - 1, x + 1);
        float a0 = 0.f, a1 = 0.f;
#pragma unroll
        for (int ky = 0; ky < 3; ++ky)
#pragma unroll
            for (int kx = 0; kx < 3; ++kx) {
                a0 += win[ky][kx].x * wq0[ky * 3 + kx];
                a1 += win[ky][kx].y * wq1[ky * 3 + kx];
            }
        a0 = 0.5f * a0 * (1.f + erff(a0 * 0.70710678118654752f));
        a1 = 0.5f * a1 * (1.f + erff(a1 * 0.70710678118654752f));
        const unsigned up = (unsigned)f2bf(a0) | ((unsigned)f2bf(a1) << 16);
        *(unsigned*)(g + (pixbase + (long)y * 128 + x) * 512 + c0) = up;
#pragma unroll
        for (int ky = 0; ky < 3; ++ky) {
            win[ky][0] = win[ky][1];
            win[ky][1] = win[ky][2];
        }
    }
}

__global__ __launch_bounds__(256)
void k_conv2_add(const unsigned short* __restrict__ gin,
                 const float* __restrict__ w, float* __restrict__ out) {
    const int x0 = blockIdx.x * 16;
    const int y  = blockIdx.y;
    const int b  = blockIdx.z;
    const int c0 = threadIdx.x * 2;
    float wq0[9], wq1[9];
#pragma unroll
    for (int i = 0; i < 9; ++i) { wq0[i] = w[c0 * 9 + i]; wq1[i] = w[(c0 + 1) * 9 + i]; }
    const long pixbase = (long)b * 16384;

    auto ld = [&](int yy, int xx) -> float2 {
        if (yy < 0 || yy > 127 || xx < 0 || xx > 127) return make_float2(0.f, 0.f);
        return bfpair(*(const unsigned*)(gin + (pixbase + (long)yy * 128 + xx) * 512 + c0));
    };

    float2 win[3][3];
#pragma unroll
    for (int ky = 0; ky < 3; ++ky) {
        win[ky][0] = ld(y + ky - 1, x0 - 1);
        win[ky][1] = ld(y + ky - 1, x0);
    }
    for (int xi = 0; xi < 16; ++xi) {
        const int x = x0 + xi;
#pragma unroll
        for (int ky = 0; ky < 3; ++ky) win[ky][2] = ld(y + ky - 1, x + 1);
        float a0 = 0.f, a1 = 0.f;
#pragma unroll
        for (int ky = 0; ky < 3; ++ky)
#pragma unroll
            for (int kx = 0; kx < 3; ++kx) {
                a0 += win[ky][kx].x * wq0[ky * 3 + kx];
                a1 += win[ky][kx].y * wq1[ky * 3 + kx];
            }
        float2* o = (float2*)(out + (pixbase + (long)y * 128 + x) * 512 + c0);
        float2 p = *o;
        p.x += a0; p.y += a1;
        *o = p;
#pragma unroll
        for (int ky = 0; ky < 3; ++ky) {
            win[ky][0] = win[ky][1];
            win[ky][1] = win[ky][2];
        }
    }
}

// ---------- launch ----------
extern "C" void kernel_launch(void* const* d_in, const int* in_sizes, int n_in,
                              void* d_out, int out_size, void* d_ws, size_t ws_size,
                              hipStream_t stream) {
    const float* x_in    = (const float*)d_in[0];
    const float* Wq      = (const float*)d_in[1];
    const float* Wk      = (const float*)d_in[2];
    const float* Wv      = (const float*)d_in[3];
    const float* rescale = (const float*)d_in[4];
    const float* Wp      = (const float*)d_in[5];
    const float* bp      = (const float*)d_in[6];
    const float* c1w     = (const float*)d_in[7];
    const float* c2w     = (const float*)d_in[8];
    float* out = (float*)d_out;

    char* ws = (char*)d_ws;
    unsigned short* XBF = (unsigned short*)(ws);                  // [65536][512] bf16; reused as gelu buf
    unsigned short* VBF = (unsigned short*)(ws + 67108864LL);     // [65536][512] bf16
    unsigned short* XT  = (unsigned short*)(ws + 134217728LL);    // [4][512][16384] bf16
    float*          P   = (float*)(ws + 201326592LL);             // [4][8][16][16384] f32 partials
    unsigned short* WCT = (unsigned short*)(ws + 234881024LL);    // [WqT;WkT;WvT] [1536][512] bf16
    unsigned short* GB  = (unsigned short*)(ws + 236453888LL);    // [4][512][512] bf16
    unsigned short* T1e = (unsigned short*)(ws + 238551040LL);    // Wq^T G  [4][512][512] bf16
    unsigned short* T2e = (unsigned short*)(ws + 240648192LL);    // Wk^T G  [4][512][512] bf16
    float*          SSQ = (float*)(ws + 242745344LL);             // [4][1024]
    float*          ATTF= (float*)(ws + 242761728LL);             // [4][512][512] f32
    unsigned short* WEF = (unsigned short*)(ws + 246956032LL);    // WeffT [4][512][512] bf16

    // fused convert + transpose
    k_cvt_tr<<<dim3(8, 1024), dim3(256), 0, stream>>>(x_in, XBF, XT);
    k_build_wcat<<<dim3(16, 48), dim3(256), 0, stream>>>(Wq, Wk, Wv, WCT);

    // V = X @ Wv  (M=65536, N=512, K=512)
    gemm_mfma<1, 0><<<dim3(4, 512, 1), dim3(256), 0, stream>>>(
        XBF, WCT + 2 * 262144, (void*)VBF, nullptr, 512, 512, 512, 512, 0L, 0L, 0L);

    // Gram matrix G = X^T X per batch: split-K m97-template GEMM on XT -> partials -> reduce
    gemm_gram<<<dim3(4, 4, 32), dim3(256), 0, stream>>>(XT, P);
    k_greduce<<<dim3(2048), dim3(256), 0, stream>>>(P, (unsigned*)GB);

    // sandwiches: T2e = WkT*GB^T, T1e = WqT*GB^T, attn = T2e*WqT^T (fp32 out)
    gemm_mfma<1, 0><<<dim3(4, 4, 4), dim3(256), 0, stream>>>(
        WCT + 262144, GB, (void*)T2e, nullptr, 512, 512, 512, 512, 0L, 262144L, 262144L);
    gemm_mfma<1, 0><<<dim3(4, 4, 4), dim3(256), 0, stream>>>(
        WCT, GB, (void*)T1e, nullptr, 512, 512, 512, 512, 0L, 262144L, 262144L);
    gemm_mfma<0, 0><<<dim3(4, 4, 4), dim3(256), 0, stream>>>(
        T2e, WCT, (void*)ATTF, nullptr, 512, 512, 512, 512, 262144L, 0L, 262144L);

    k_ssq<<<dim3(4, 4), dim3(256), 0, stream>>>(WCT, T1e, T2e, SSQ);
    k_softmax<<<dim3(32), dim3(64), 0, stream>>>(ATTF, SSQ, rescale);
    k_weff<<<dim3(8, 4), dim3(256), 0, stream>>>(ATTF, Wp, WEF);

    // out_c = V @ Weff^T + bp  (batched: M=16384, N=512, K=512)
    gemm_mfma<0, 1><<<dim3(4, 128, 4), dim3(256), 0, stream>>>(
        VBF, WEF, (void*)out, bp, 512, 512, 512, 512,
        (long)16384 * 512, 262144L, (long)16384 * 512);

    // positional branch: dwconv3x3 -> gelu -> dwconv3x3, += into out
    k_conv1_gelu<<<dim3(8, 128, 4), dim3(256), 0, stream>>>(VBF, c1w, XBF);
    k_conv2_add<<<dim3(8, 128, 4), dim3(256), 0, stream>>>(XBF, c2w, out);
}

// Round 9
// 501.234 us; speedup vs baseline: 1.5141x; 1.0599x over previous
//
#include <hip/hip_runtime.h>
#include <hip/hip_bf16.h>

// ---------- types & helpers ----------
typedef __attribute__((ext_vector_type(4))) float f32x4;
typedef __attribute__((ext_vector_type(8))) short s16x8;

__device__ __forceinline__ unsigned short f2bf(float f) {
    __hip_bfloat16 h = __float2bfloat16(f);
    return __builtin_bit_cast(unsigned short, h);
}
__device__ __forceinline__ float bf2f(unsigned short u) {
    return __builtin_bit_cast(float, ((unsigned)u) << 16);
}
__device__ __forceinline__ float2 bfpair(unsigned u) {
    float2 r;
    r.x = __builtin_bit_cast(float, u << 16);
    r.y = __builtin_bit_cast(float, u & 0xffff0000u);
    return r;
}
__device__ __forceinline__ void gload_lds16(const void* g, void* l) {
    __builtin_amdgcn_global_load_lds(
        (const __attribute__((address_space(1))) void*)g,
        (__attribute__((address_space(3))) void*)l, 16, 0, 0);
}

// ---------- fused fp32->bf16 convert + transpose ----------
__global__ __launch_bounds__(256)
void k_cvt_tr(const float* __restrict__ in, unsigned short* __restrict__ XBF,
              unsigned short* __restrict__ XT) {
    __shared__ __align__(16) unsigned short tile[64 * 64];
    const int t  = threadIdx.x;
    const int c0 = blockIdx.x * 64;
    const int ty = blockIdx.y;
    const long tokg = (long)ty * 64;
    const int cq = t & 15, r0 = t >> 4;
#pragma unroll
    for (int p = 0; p < 4; ++p) {
        const int tok = r0 + p * 16;
        const float4 v = *(const float4*)(in + (tokg + tok) * 512 + c0 + cq * 4);
        union { unsigned short h[4]; uint2 u; } pk;
        pk.h[0] = f2bf(v.x); pk.h[1] = f2bf(v.y); pk.h[2] = f2bf(v.z); pk.h[3] = f2bf(v.w);
        *(uint2*)(XBF + (tokg + tok) * 512 + c0 + cq * 4) = pk.u;
        const int T = tok >> 3, i = tok & 7;
#pragma unroll
        for (int j = 0; j < 4; ++j) {
            const int c = cq * 4 + j;
            tile[c * 64 + ((T ^ (c & 7)) * 8 + i)] = pk.h[j];
        }
    }
    __syncthreads();
    const int b  = ty >> 8;
    const long tb = (long)(ty & 255) * 64;
    const int T2 = t & 7;
#pragma unroll
    for (int q = 0; q < 2; ++q) {
        const int c = (t >> 3) + q * 32;
        const uint4 v = *(const uint4*)&tile[c * 64 + ((T2 ^ (c & 7)) * 8)];
        *(uint4*)(XT + ((long)(b * 512 + c0 + c)) * 16384 + tb + T2 * 8) = v;
    }
}

// ---------- build [WqT; WkT; WvT] bf16 [1536][512] via LDS 32x32 transpose ----------
__global__ __launch_bounds__(256)
void k_build_wcat(const float* __restrict__ Wq, const float* __restrict__ Wk,
                  const float* __restrict__ Wv, unsigned short* __restrict__ WcatT) {
    __shared__ float t[32][33];
    const int k0 = blockIdx.x * 32;
    const int j0 = blockIdx.y * 32;
    const float* src = (j0 < 512) ? Wq : (j0 < 1024 ? Wk : Wv);
    const int jc0 = j0 & 511;
    const int r = threadIdx.x >> 5, c = threadIdx.x & 31;
#pragma unroll
    for (int rr = 0; rr < 4; ++rr) {
        const int k = k0 + r + rr * 8;
        t[c][r + rr * 8] = src[(long)k * 512 + jc0 + c];
    }
    __syncthreads();
#pragma unroll
    for (int rr = 0; rr < 4; ++rr) {
        const int j = j0 + r + rr * 8;
        WcatT[(long)j * 512 + k0 + c] = f2bf(t[r + rr * 8][c]);
    }
}

// ---------- MFMA bf16 GEMM 128x128 (m97-style): C[M,N] = A[M,K] * B[N,K]^T ----------
#define BM 128
#define BN 128
#define BK 64

template<int OUT_BF16, int BIAS>
__global__ __launch_bounds__(256, 2)
void gemm_mfma(const unsigned short* __restrict__ A, const unsigned short* __restrict__ B,
               void* __restrict__ C_, const float* __restrict__ bias,
               int lda, int ldb, int ldc, int K, long sA, long sB, long sC) {
    __shared__ __align__(16) unsigned short As[BM * BK];
    __shared__ __align__(16) unsigned short Bs[BN * BK];
    const int tid  = threadIdx.x;
    const int wave = tid >> 6;
    const int lane = tid & 63;
    const int wm = wave >> 1, wn = wave & 1;
    const int bm0 = blockIdx.y * BM;
    const int bn0 = blockIdx.x * BN;
    const long bz = blockIdx.z;
    A += bz * sA;
    B += bz * sB;

    const int l15 = lane & 15;
    const int l4  = lane >> 4;

    f32x4 acc[4][4];
#pragma unroll
    for (int i = 0; i < 4; ++i)
#pragma unroll
        for (int j = 0; j < 4; ++j) acc[i][j] = (f32x4){0.f, 0.f, 0.f, 0.f};

    const int srow    = wave * 8 + (lane >> 3);
    const int schunk0 = lane & 7;
    const int arow_b  = wm * 64 + l15;
    const int brow_b  = wn * 64 + l15;

    const int nk = K / BK;
    for (int kt = 0; kt < nk; ++kt) {
        const int k0 = kt * BK;
#pragma unroll
        for (int i = 0; i < 4; ++i) {
            const int r  = i * 32 + srow;
            const int gc = schunk0 ^ (r & 7);
            gload_lds16(A + (long)(bm0 + r) * lda + (k0 + gc * 8), &As[(i * 32 + wave * 8) * BK]);
            gload_lds16(B + (long)(bn0 + r) * ldb + (k0 + gc * 8), &Bs[(i * 32 + wave * 8) * BK]);
        }
        __syncthreads();
        s16x8 af[4][2], bfr[4][2];
#pragma unroll
        for (int mi = 0; mi < 4; ++mi) {
            const int row = arow_b + mi * 16;
#pragma unroll
            for (int ki = 0; ki < 2; ++ki) {
                const int ch = (ki * 4 + l4) ^ (row & 7);
                af[mi][ki] = *(const s16x8*)&As[row * BK + ch * 8];
            }
        }
#pragma unroll
        for (int ni = 0; ni < 4; ++ni) {
            const int row = brow_b + ni * 16;
#pragma unroll
            for (int ki = 0; ki < 2; ++ki) {
                const int ch = (ki * 4 + l4) ^ (row & 7);
                bfr[ni][ki] = *(const s16x8*)&Bs[row * BK + ch * 8];
            }
        }
#pragma unroll
        for (int ki = 0; ki < 2; ++ki)
#pragma unroll
            for (int mi = 0; mi < 4; ++mi)
#pragma unroll
                for (int ni = 0; ni < 4; ++ni)
                    acc[mi][ni] = __builtin_amdgcn_mfma_f32_16x16x32_bf16(
                        af[mi][ki], bfr[ni][ki], acc[mi][ni], 0, 0, 0);
        __syncthreads();
    }

#pragma unroll
    for (int mi = 0; mi < 4; ++mi) {
        const int row0 = bm0 + wm * 64 + mi * 16 + l4 * 4;
#pragma unroll
        for (int ni = 0; ni < 4; ++ni) {
            const int col = bn0 + wn * 64 + ni * 16 + l15;
            if (OUT_BF16) {
                unsigned short* C = (unsigned short*)C_ + bz * sC;
#pragma unroll
                for (int j = 0; j < 4; ++j)
                    C[(long)(row0 + j) * ldc + col] = f2bf(acc[mi][ni][j]);
            } else {
                float* C = (float*)C_ + bz * sC;
                const float bv = BIAS ? bias[col] : 0.f;
#pragma unroll
                for (int j = 0; j < 4; ++j)
                    C[(long)(row0 + j) * ldc + col] = acc[mi][ni][j] + bv;
            }
        }
    }
}

// ---------- Gram split-K: m97 template on XT ----------
__global__ __launch_bounds__(256, 2)
void gemm_gram(const unsigned short* __restrict__ XT, float* __restrict__ P) {
    __shared__ __align__(16) unsigned short As[128 * 64];
    __shared__ __align__(16) unsigned short Bs[128 * 64];
    const int tid = threadIdx.x, wave = tid >> 6, lane = tid & 63;
    const int wm = wave >> 1, wn = wave & 1;
    const int bm0 = blockIdx.y * 128, bn0 = blockIdx.x * 128;
    const int z = blockIdx.z, b = z >> 3, chunk = z & 7;
    const unsigned short* A = XT + (long)b * 512 * 16384;
    const int l15 = lane & 15, l4 = lane >> 4;

    f32x4 acc[4][4];
#pragma unroll
    for (int i = 0; i < 4; ++i)
#pragma unroll
        for (int j = 0; j < 4; ++j) acc[i][j] = (f32x4){0.f, 0.f, 0.f, 0.f};

    const int srow = wave * 8 + (lane >> 3);
    const int sch  = lane & 7;
    const int arow_b = wm * 64 + l15;
    const int brow_b = wn * 64 + l15;

    for (int kt = 0; kt < 32; ++kt) {
        const long k0 = (long)chunk * 2048 + kt * 64;
#pragma unroll
        for (int i = 0; i < 4; ++i) {
            const int r  = i * 32 + srow;
            const int gc = sch ^ (r & 7);
            gload_lds16(A + (long)(bm0 + r) * 16384 + k0 + gc * 8, &As[(i * 32 + wave * 8) * 64]);
            gload_lds16(A + (long)(bn0 + r) * 16384 + k0 + gc * 8, &Bs[(i * 32 + wave * 8) * 64]);
        }
        __syncthreads();
        s16x8 af[4][2], bfr[4][2];
#pragma unroll
        for (int mi = 0; mi < 4; ++mi) {
            const int row = arow_b + mi * 16;
#pragma unroll
            for (int ki = 0; ki < 2; ++ki)
                af[mi][ki] = *(const s16x8*)&As[row * 64 + (((ki * 4 + l4) ^ (row & 7))) * 8];
        }
#pragma unroll
        for (int ni = 0; ni < 4; ++ni) {
            const int row = brow_b + ni * 16;
#pragma unroll
            for (int ki = 0; ki < 2; ++ki)
                bfr[ni][ki] = *(const s16x8*)&Bs[row * 64 + (((ki * 4 + l4) ^ (row & 7))) * 8];
        }
#pragma unroll
        for (int ki = 0; ki < 2; ++ki)
#pragma unroll
            for (int mi = 0; mi < 4; ++mi)
#pragma unroll
                for (int ni = 0; ni < 4; ++ni)
                    acc[mi][ni] = __builtin_amdgcn_mfma_f32_16x16x32_bf16(
                        af[mi][ki], bfr[ni][ki], acc[mi][ni], 0, 0, 0);
        __syncthreads();
    }

    float* Pb = P + ((long)((b * 8 + chunk) * 16 + blockIdx.y * 4 + blockIdx.x)) * 16384;
#pragma unroll
    for (int mi = 0; mi < 4; ++mi) {
        const int row0 = wm * 64 + mi * 16 + l4 * 4;
#pragma unroll
        for (int ni = 0; ni < 4; ++ni) {
            const int col = wn * 64 + ni * 16 + l15;
#pragma unroll
            for (int j = 0; j < 4; ++j)
                Pb[(row0 + j) * 128 + col] = acc[mi][ni][j];
        }
    }
}

// ---------- reduce partials over chunks -> GB bf16 [4][512][512] ----------
__global__ void k_greduce(const float* __restrict__ P, unsigned* __restrict__ GB2) {
    const long idx = (long)blockIdx.x * 256 + threadIdx.x;
    const int b   = (int)(idx >> 17);
    const int rem = (int)(idx & 131071);
    const int c   = rem >> 8;
    const int cp0 = (rem & 255) * 2;
    const int tp  = (c >> 7) * 4 + (cp0 >> 7);
    const int e   = (c & 127) * 128 + (cp0 & 127);
    const float* Pp = P + ((long)(b * 8) * 16 + tp) * 16384 + e;
    float s0 = 0.f, s1 = 0.f;
#pragma unroll
    for (int ch = 0; ch < 8; ++ch) {
        const float2 v = *(const float2*)(Pp + (long)ch * 16 * 16384);
        s0 += v.x; s1 += v.y;
    }
    GB2[idx] = (unsigned)f2bf(s0) | ((unsigned)f2bf(s1) << 16);
}

// ---------- row-dots for sumsq ----------
__global__ void k_ssq(const unsigned short* __restrict__ WCT, const unsigned short* __restrict__ T1e,
                      const unsigned short* __restrict__ T2e, float* __restrict__ SSQ) {
    const int b = blockIdx.y;
    const int o = blockIdx.x * 256 + threadIdx.x;
    const unsigned short* wrow;
    const unsigned short* trow;
    if (o < 512) {
        wrow = WCT + (long)o * 512;
        trow = T1e + (long)b * 262144 + (long)o * 512;
    } else {
        const int d = o - 512;
        wrow = WCT + 262144 + (long)d * 512;
        trow = T2e + (long)b * 262144 + (long)d * 512;
    }
    float s = 0.f;
    for (int c = 0; c < 512; c += 8) {
        const s16x8 w = *(const s16x8*)&wrow[c];
        const s16x8 v = *(const s16x8*)&trow[c];
#pragma unroll
        for (int j = 0; j < 8; ++j)
            s += bf2f((unsigned short)w[j]) * bf2f((unsigned short)v[j]);
    }
    SSQ[b * 1024 + o] = s;
}

// ---------- wave-parallel normalize + softmax: one wave per (b,h,d) row ----------
__global__ __launch_bounds__(256)
void k_softmax(float* __restrict__ attn, const float* __restrict__ sumsq,
               const float* __restrict__ rescale) {
    const int wid = (blockIdx.x * 256 + threadIdx.x) >> 6;   // 0..2047
    const int e   = threadIdx.x & 63;
    const int b = wid >> 9, rem = wid & 511;
    const int h = rem >> 6, d = rem & 63;
    const float rs   = rescale[h];
    const float invk = rsqrtf(sumsq[b * 1024 + 512 + h * 64 + d]);
    const float invq = rsqrtf(sumsq[b * 1024 + h * 64 + e]);
    float* row = attn + ((long)b * 512 + h * 64 + d) * 512 + h * 64;
    const float v = row[e] * invk * invq * rs;
    float mx = v;
#pragma unroll
    for (int off = 32; off >= 1; off >>= 1) mx = fmaxf(mx, __shfl_xor(mx, off));
    const float l = expf(v - mx);
    float s = l;
#pragma unroll
    for (int off = 32; off >= 1; off >>= 1) s += __shfl_xor(s, off);
    row[e] = l / s;
}

// ---------- Weff^T[b][cout][h*64+e] = sum_d attn[b,h,d,e] * Wp[h*64+d][cout] ----------
__global__ __launch_bounds__(256)
void k_weff(const float* __restrict__ attn, const float* __restrict__ Wp,
            unsigned short* __restrict__ WeffT) {
    const int h = blockIdx.x, b = blockIdx.y;
    __shared__ float At[64 * 64];   // [d][e]
    __shared__ float Wt[64 * 128];  // [d][c]
    const int t = threadIdx.x;
    const float* arow = attn + ((long)b * 512 + h * 64) * 512 + h * 64;
    for (int i = 0; i < 16; ++i) {
        const int idx = i * 256 + t;
        const int d = idx >> 6, e = idx & 63;
        At[idx] = arow[(long)d * 512 + e];
    }
    const int e = t & 63, cs = t >> 6;
    for (int cc = 0; cc < 512; cc += 128) {
        __syncthreads();
        for (int i = 0; i < 32; ++i) {
            const int idx = i * 256 + t;
            const int d = idx >> 7, c = idx & 127;
            Wt[idx] = Wp[(long)(h * 64 + d) * 512 + cc + c];
        }
        __syncthreads();
        for (int i = 0; i < 32; ++i) {
            const int cl = cs * 32 + i;
            float acc = 0.f;
#pragma unroll
            for (int d = 0; d < 64; ++d) acc += At[d * 64 + e] * Wt[d * 128 + cl];
            WeffT[((long)b * 512 + cc + cl) * 512 + h * 64 + e] = f2bf(acc);
        }
    }
}

// ---------- depthwise 3x3 conv, x-unrolled x4 for memory ILP ----------
__global__ __launch_bounds__(256)
void k_conv1_gelu(const unsigned short* __restrict__ V,   // pixel stride 512
                  const float* __restrict__ w, unsigned short* __restrict__ g) {
    const int x0 = blockIdx.x * 16;
    const int y  = blockIdx.y;
    const int b  = blockIdx.z;
    const int c0 = threadIdx.x * 2;
    float wq0[9], wq1[9];
#pragma unroll
    for (int i = 0; i < 9; ++i) { wq0[i] = w[c0 * 9 + i]; wq1[i] = w[(c0 + 1) * 9 + i]; }
    const long pixbase = (long)b * 16384;

    auto ld = [&](int yy, int xx) -> float2 {
        if (yy < 0 || yy > 127 || xx < 0 || xx > 127) return make_float2(0.f, 0.f);
        return bfpair(*(const unsigned*)(V + (pixbase + (long)yy * 128 + xx) * 512 + c0));
    };

    float2 col[3][6];
#pragma unroll
    for (int ky = 0; ky < 3; ++ky) {
        col[ky][0] = ld(y + ky - 1, x0 - 1);
        col[ky][1] = ld(y + ky - 1, x0);
    }
    for (int xq = 0; xq < 4; ++xq) {
        const int xb = x0 + xq * 4;
        // batch-load 12 new columns
#pragma unroll
        for (int ky = 0; ky < 3; ++ky)
#pragma unroll
            for (int j = 0; j < 4; ++j)
                col[ky][2 + j] = ld(y + ky - 1, xb + 1 + j);
        // compute + store 4 outputs
#pragma unroll
        for (int j = 0; j < 4; ++j) {
            float a0 = 0.f, a1 = 0.f;
#pragma unroll
            for (int ky = 0; ky < 3; ++ky)
#pragma unroll
                for (int kx = 0; kx < 3; ++kx) {
                    a0 += col[ky][j + kx].x * wq0[ky * 3 + kx];
                    a1 += col[ky][j + kx].y * wq1[ky * 3 + kx];
                }
            a0 = 0.5f * a0 * (1.f + erff(a0 * 0.70710678118654752f));
            a1 = 0.5f * a1 * (1.f + erff(a1 * 0.70710678118654752f));
            const unsigned up = (unsigned)f2bf(a0) | ((unsigned)f2bf(a1) << 16);
            *(unsigned*)(g + (pixbase + (long)y * 128 + xb + j) * 512 + c0) = up;
        }
#pragma unroll
        for (int ky = 0; ky < 3; ++ky) {
            col[ky][0] = col[ky][4];
            col[ky][1] = col[ky][5];
        }
    }
}

__global__ __launch_bounds__(256)
void k_conv2_add(const unsigned short* __restrict__ gin,
                 const float* __restrict__ w, float* __restrict__ out) {
    const int x0 = blockIdx.x * 16;
    const int y  = blockIdx.y;
    const int b  = blockIdx.z;
    const int c0 = threadIdx.x * 2;
    float wq0[9], wq1[9];
#pragma unroll
    for (int i = 0; i < 9; ++i) { wq0[i] = w[c0 * 9 + i]; wq1[i] = w[(c0 + 1) * 9 + i]; }
    const long pixbase = (long)b * 16384;

    auto ld = [&](int yy, int xx) -> float2 {
        if (yy < 0 || yy > 127 || xx < 0 || xx > 127) return make_float2(0.f, 0.f);
        return bfpair(*(const unsigned*)(gin + (pixbase + (long)yy * 128 + xx) * 512 + c0));
    };

    float2 col[3][6];
#pragma unroll
    for (int ky = 0; ky < 3; ++ky) {
        col[ky][0] = ld(y + ky - 1, x0 - 1);
        col[ky][1] = ld(y + ky - 1, x0);
    }
    for (int xq = 0; xq < 4; ++xq) {
        const int xb = x0 + xq * 4;
#pragma unroll
        for (int ky = 0; ky < 3; ++ky)
#pragma unroll
            for (int j = 0; j < 4; ++j)
                col[ky][2 + j] = ld(y + ky - 1, xb + 1 + j);
        // batch the 4 RMW reads
        float2* optr[4];
        float2 pv[4];
#pragma unroll
        for (int j = 0; j < 4; ++j) {
            optr[j] = (float2*)(out + (pixbase + (long)y * 128 + xb + j) * 512 + c0);
            pv[j] = *optr[j];
        }
#pragma unroll
        for (int j = 0; j < 4; ++j) {
            float a0 = 0.f, a1 = 0.f;
#pragma unroll
            for (int ky = 0; ky < 3; ++ky)
#pragma unroll
                for (int kx = 0; kx < 3; ++kx) {
                    a0 += col[ky][j + kx].x * wq0[ky * 3 + kx];
                    a1 += col[ky][j + kx].y * wq1[ky * 3 + kx];
                }
            pv[j].x += a0; pv[j].y += a1;
            *optr[j] = pv[j];
        }
#pragma unroll
        for (int ky = 0; ky < 3; ++ky) {
            col[ky][0] = col[ky][4];
            col[ky][1] = col[ky][5];
        }
    }
}

// ---------- launch ----------
extern "C" void kernel_launch(void* const* d_in, const int* in_sizes, int n_in,
                              void* d_out, int out_size, void* d_ws, size_t ws_size,
                              hipStream_t stream) {
    const float* x_in    = (const float*)d_in[0];
    const float* Wq      = (const float*)d_in[1];
    const float* Wk      = (const float*)d_in[2];
    const float* Wv      = (const float*)d_in[3];
    const float* rescale = (const float*)d_in[4];
    const float* Wp      = (const float*)d_in[5];
    const float* bp      = (const float*)d_in[6];
    const float* c1w     = (const float*)d_in[7];
    const float* c2w     = (const float*)d_in[8];
    float* out = (float*)d_out;

    char* ws = (char*)d_ws;
    unsigned short* XBF = (unsigned short*)(ws);                  // [65536][512] bf16; reused as gelu buf
    unsigned short* VBF = (unsigned short*)(ws + 67108864LL);     // [65536][512] bf16
    unsigned short* XT  = (unsigned short*)(ws + 134217728LL);    // [4][512][16384] bf16
    float*          P   = (float*)(ws + 201326592LL);             // [4][8][16][16384] f32 partials
    unsigned short* WCT = (unsigned short*)(ws + 234881024LL);    // [WqT;WkT;WvT] [1536][512] bf16
    unsigned short* GB  = (unsigned short*)(ws + 236453888LL);    // [4][512][512] bf16
    unsigned short* T1e = (unsigned short*)(ws + 238551040LL);    // Wq^T G
    unsigned short* T2e = (unsigned short*)(ws + 240648192LL);    // Wk^T G
    float*          SSQ = (float*)(ws + 242745344LL);             // [4][1024]
    float*          ATTF= (float*)(ws + 242761728LL);             // [4][512][512] f32
    unsigned short* WEF = (unsigned short*)(ws + 246956032LL);    // WeffT

    k_cvt_tr<<<dim3(8, 1024), dim3(256), 0, stream>>>(x_in, XBF, XT);
    k_build_wcat<<<dim3(16, 48), dim3(256), 0, stream>>>(Wq, Wk, Wv, WCT);

    // V = X @ Wv
    gemm_mfma<1, 0><<<dim3(4, 512, 1), dim3(256), 0, stream>>>(
        XBF, WCT + 2 * 262144, (void*)VBF, nullptr, 512, 512, 512, 512, 0L, 0L, 0L);

    // Gram matrix
    gemm_gram<<<dim3(4, 4, 32), dim3(256), 0, stream>>>(XT, P);
    k_greduce<<<dim3(2048), dim3(256), 0, stream>>>(P, (unsigned*)GB);

    // sandwiches
    gemm_mfma<1, 0><<<dim3(4, 4, 4), dim3(256), 0, stream>>>(
        WCT + 262144, GB, (void*)T2e, nullptr, 512, 512, 512, 512, 0L, 262144L, 262144L);
    gemm_mfma<1, 0><<<dim3(4, 4, 4), dim3(256), 0, stream>>>(
        WCT, GB, (void*)T1e, nullptr, 512, 512, 512, 512, 0L, 262144L, 262144L);
    gemm_mfma<0, 0><<<dim3(4, 4, 4), dim3(256), 0, stream>>>(
        T2e, WCT, (void*)ATTF, nullptr, 512, 512, 512, 512, 262144L, 0L, 262144L);

    k_ssq<<<dim3(4, 4), dim3(256), 0, stream>>>(WCT, T1e, T2e, SSQ);
    k_softmax<<<dim3(512), dim3(256), 0, stream>>>(ATTF, SSQ, rescale);
    k_weff<<<dim3(8, 4), dim3(256), 0, stream>>>(ATTF, Wp, WEF);

    // out_c = V @ Weff^T + bp
    gemm_mfma<0, 1><<<dim3(4, 128, 4), dim3(256), 0, stream>>>(
        VBF, WEF, (void*)out, bp, 512, 512, 512, 512,
        (long)16384 * 512, 262144L, (long)16384 * 512);

    // positional branch
    k_conv1_gelu<<<dim3(8, 128, 4), dim3(256), 0, stream>>>(VBF, c1w, XBF);
    k_conv2_add<<<dim3(8, 128, 4), dim3(256), 0, stream>>>(XBF, c2w, out);
}

// Round 10
// 395.496 us; speedup vs baseline: 1.9190x; 1.2674x over previous
//
#include <hip/hip_runtime.h>
#include <hip/hip_bf16.h>

// ---------- types & helpers ----------
typedef __attribute__((ext_vector_type(4))) float f32x4;
typedef __attribute__((ext_vector_type(8))) short s16x8;

__device__ __forceinline__ unsigned short f2bf(float f) {
    __hip_bfloat16 h = __float2bfloat16(f);
    return __builtin_bit_cast(unsigned short, h);
}
__device__ __forceinline__ float bf2f(unsigned short u) {
    return __builtin_bit_cast(float, ((unsigned)u) << 16);
}
__device__ __forceinline__ float2 bfpair(unsigned u) {
    float2 r;
    r.x = __builtin_bit_cast(float, u << 16);
    r.y = __builtin_bit_cast(float, u & 0xffff0000u);
    return r;
}
__device__ __forceinline__ void gload_lds16(const void* g, void* l) {
    __builtin_amdgcn_global_load_lds(
        (const __attribute__((address_space(1))) void*)g,
        (__attribute__((address_space(3))) void*)l, 16, 0, 0);
}
__device__ __forceinline__ float gelu_tanh(float x) {
    const float y = 0.7978845608028654f * (x + 0.044715f * x * x * x);
    const float t = __expf(-2.f * fabsf(y));
    const float th = (1.f - t) / (1.f + t);
    return 0.5f * x * (1.f + copysignf(th, y));
}

// ---------- fused fp32->bf16 convert + transpose ----------
__global__ __launch_bounds__(256)
void k_cvt_tr(const float* __restrict__ in, unsigned short* __restrict__ XBF,
              unsigned short* __restrict__ XT) {
    __shared__ __align__(16) unsigned short tile[64 * 64];
    const int t  = threadIdx.x;
    const int c0 = blockIdx.x * 64;
    const int ty = blockIdx.y;
    const long tokg = (long)ty * 64;
    const int cq = t & 15, r0 = t >> 4;
#pragma unroll
    for (int p = 0; p < 4; ++p) {
        const int tok = r0 + p * 16;
        const float4 v = *(const float4*)(in + (tokg + tok) * 512 + c0 + cq * 4);
        union { unsigned short h[4]; uint2 u; } pk;
        pk.h[0] = f2bf(v.x); pk.h[1] = f2bf(v.y); pk.h[2] = f2bf(v.z); pk.h[3] = f2bf(v.w);
        *(uint2*)(XBF + (tokg + tok) * 512 + c0 + cq * 4) = pk.u;
        const int T = tok >> 3, i = tok & 7;
#pragma unroll
        for (int j = 0; j < 4; ++j) {
            const int c = cq * 4 + j;
            tile[c * 64 + ((T ^ (c & 7)) * 8 + i)] = pk.h[j];
        }
    }
    __syncthreads();
    const int b  = ty >> 8;
    const long tb = (long)(ty & 255) * 64;
    const int T2 = t & 7;
#pragma unroll
    for (int q = 0; q < 2; ++q) {
        const int c = (t >> 3) + q * 32;
        const uint4 v = *(const uint4*)&tile[c * 64 + ((T2 ^ (c & 7)) * 8)];
        *(uint4*)(XT + ((long)(b * 512 + c0 + c)) * 16384 + tb + T2 * 8) = v;
    }
}

// ---------- build [WqT; WkT; WvT; WpT] bf16 [2048][512] via LDS 32x32 transpose ----------
__global__ __launch_bounds__(256)
void k_build_wcat(const float* __restrict__ Wq, const float* __restrict__ Wk,
                  const float* __restrict__ Wv, const float* __restrict__ Wp,
                  unsigned short* __restrict__ WcatT) {
    __shared__ float t[32][33];
    const int k0 = blockIdx.x * 32;
    const int j0 = blockIdx.y * 32;
    const float* src = (j0 < 512) ? Wq : (j0 < 1024 ? Wk : (j0 < 1536 ? Wv : Wp));
    const int jc0 = j0 & 511;
    const int r = threadIdx.x >> 5, c = threadIdx.x & 31;
#pragma unroll
    for (int rr = 0; rr < 4; ++rr) {
        const int k = k0 + r + rr * 8;
        t[c][r + rr * 8] = src[(long)k * 512 + jc0 + c];
    }
    __syncthreads();
#pragma unroll
    for (int rr = 0; rr < 4; ++rr) {
        const int j = j0 + r + rr * 8;
        WcatT[(long)j * 512 + k0 + c] = f2bf(t[r + rr * 8][c]);
    }
}

// ---------- MFMA bf16 GEMM 128x128 (m97-style): C[M,N] = A[M,K] * B[N,K]^T ----------
#define BM 128
#define BN 128
#define BK 64

template<int OUT_BF16, int BIAS, int ADDC>
__global__ __launch_bounds__(256, 2)
void gemm_mfma(const unsigned short* __restrict__ A, const unsigned short* __restrict__ B,
               void* __restrict__ C_, const float* __restrict__ bias,
               const unsigned short* __restrict__ addc,
               int lda, int ldb, int ldc, int K, long sA, long sB, long sC) {
    __shared__ __align__(16) unsigned short As[BM * BK];
    __shared__ __align__(16) unsigned short Bs[BN * BK];
    const int tid  = threadIdx.x;
    const int wave = tid >> 6;
    const int lane = tid & 63;
    const int wm = wave >> 1, wn = wave & 1;
    const int bm0 = blockIdx.y * BM;
    const int bn0 = blockIdx.x * BN;
    const long bz = blockIdx.z;
    A += bz * sA;
    B += bz * sB;

    const int l15 = lane & 15;
    const int l4  = lane >> 4;

    f32x4 acc[4][4];
#pragma unroll
    for (int i = 0; i < 4; ++i)
#pragma unroll
        for (int j = 0; j < 4; ++j) acc[i][j] = (f32x4){0.f, 0.f, 0.f, 0.f};

    const int srow    = wave * 8 + (lane >> 3);
    const int schunk0 = lane & 7;
    const int arow_b  = wm * 64 + l15;
    const int brow_b  = wn * 64 + l15;

    const int nk = K / BK;
    for (int kt = 0; kt < nk; ++kt) {
        const int k0 = kt * BK;
#pragma unroll
        for (int i = 0; i < 4; ++i) {
            const int r  = i * 32 + srow;
            const int gc = schunk0 ^ (r & 7);
            gload_lds16(A + (long)(bm0 + r) * lda + (k0 + gc * 8), &As[(i * 32 + wave * 8) * BK]);
            gload_lds16(B + (long)(bn0 + r) * ldb + (k0 + gc * 8), &Bs[(i * 32 + wave * 8) * BK]);
        }
        __syncthreads();
        s16x8 af[4][2], bfr[4][2];
#pragma unroll
        for (int mi = 0; mi < 4; ++mi) {
            const int row = arow_b + mi * 16;
#pragma unroll
            for (int ki = 0; ki < 2; ++ki) {
                const int ch = (ki * 4 + l4) ^ (row & 7);
                af[mi][ki] = *(const s16x8*)&As[row * BK + ch * 8];
            }
        }
#pragma unroll
        for (int ni = 0; ni < 4; ++ni) {
            const int row = brow_b + ni * 16;
#pragma unroll
            for (int ki = 0; ki < 2; ++ki) {
                const int ch = (ki * 4 + l4) ^ (row & 7);
                bfr[ni][ki] = *(const s16x8*)&Bs[row * BK + ch * 8];
            }
        }
#pragma unroll
        for (int ki = 0; ki < 2; ++ki)
#pragma unroll
            for (int mi = 0; mi < 4; ++mi)
#pragma unroll
                for (int ni = 0; ni < 4; ++ni)
                    acc[mi][ni] = __builtin_amdgcn_mfma_f32_16x16x32_bf16(
                        af[mi][ki], bfr[ni][ki], acc[mi][ni], 0, 0, 0);
        __syncthreads();
    }

#pragma unroll
    for (int mi = 0; mi < 4; ++mi) {
        const int row0 = bm0 + wm * 64 + mi * 16 + l4 * 4;
#pragma unroll
        for (int ni = 0; ni < 4; ++ni) {
            const int col = bn0 + wn * 64 + ni * 16 + l15;
            if (OUT_BF16) {
                unsigned short* C = (unsigned short*)C_ + bz * sC;
#pragma unroll
                for (int j = 0; j < 4; ++j)
                    C[(long)(row0 + j) * ldc + col] = f2bf(acc[mi][ni][j]);
            } else {
                float* C = (float*)C_ + bz * sC;
                const float bv = BIAS ? bias[col] : 0.f;
#pragma unroll
                for (int j = 0; j < 4; ++j) {
                    float v = acc[mi][ni][j] + bv;
                    if (ADDC) v += bf2f(addc[bz * sC + (long)(row0 + j) * ldc + col]);
                    C[(long)(row0 + j) * ldc + col] = v;
                }
            }
        }
    }
}

// ---------- Gram split-K: m97 template on XT ----------
__global__ __launch_bounds__(256, 2)
void gemm_gram(const unsigned short* __restrict__ XT, float* __restrict__ P) {
    __shared__ __align__(16) unsigned short As[128 * 64];
    __shared__ __align__(16) unsigned short Bs[128 * 64];
    const int tid = threadIdx.x, wave = tid >> 6, lane = tid & 63;
    const int wm = wave >> 1, wn = wave & 1;
    const int bm0 = blockIdx.y * 128, bn0 = blockIdx.x * 128;
    const int z = blockIdx.z, b = z >> 3, chunk = z & 7;
    const unsigned short* A = XT + (long)b * 512 * 16384;
    const int l15 = lane & 15, l4 = lane >> 4;

    f32x4 acc[4][4];
#pragma unroll
    for (int i = 0; i < 4; ++i)
#pragma unroll
        for (int j = 0; j < 4; ++j) acc[i][j] = (f32x4){0.f, 0.f, 0.f, 0.f};

    const int srow = wave * 8 + (lane >> 3);
    const int sch  = lane & 7;
    const int arow_b = wm * 64 + l15;
    const int brow_b = wn * 64 + l15;

    for (int kt = 0; kt < 32; ++kt) {
        const long k0 = (long)chunk * 2048 + kt * 64;
#pragma unroll
        for (int i = 0; i < 4; ++i) {
            const int r  = i * 32 + srow;
            const int gc = sch ^ (r & 7);
            gload_lds16(A + (long)(bm0 + r) * 16384 + k0 + gc * 8, &As[(i * 32 + wave * 8) * 64]);
            gload_lds16(A + (long)(bn0 + r) * 16384 + k0 + gc * 8, &Bs[(i * 32 + wave * 8) * 64]);
        }
        __syncthreads();
        s16x8 af[4][2], bfr[4][2];
#pragma unroll
        for (int mi = 0; mi < 4; ++mi) {
            const int row = arow_b + mi * 16;
#pragma unroll
            for (int ki = 0; ki < 2; ++ki)
                af[mi][ki] = *(const s16x8*)&As[row * 64 + (((ki * 4 + l4) ^ (row & 7))) * 8];
        }
#pragma unroll
        for (int ni = 0; ni < 4; ++ni) {
            const int row = brow_b + ni * 16;
#pragma unroll
            for (int ki = 0; ki < 2; ++ki)
                bfr[ni][ki] = *(const s16x8*)&Bs[row * 64 + (((ki * 4 + l4) ^ (row & 7))) * 8];
        }
#pragma unroll
        for (int ki = 0; ki < 2; ++ki)
#pragma unroll
            for (int mi = 0; mi < 4; ++mi)
#pragma unroll
                for (int ni = 0; ni < 4; ++ni)
                    acc[mi][ni] = __builtin_amdgcn_mfma_f32_16x16x32_bf16(
                        af[mi][ki], bfr[ni][ki], acc[mi][ni], 0, 0, 0);
        __syncthreads();
    }

    float* Pb = P + ((long)((b * 8 + chunk) * 16 + blockIdx.y * 4 + blockIdx.x)) * 16384;
#pragma unroll
    for (int mi = 0; mi < 4; ++mi) {
        const int row0 = wm * 64 + mi * 16 + l4 * 4;
#pragma unroll
        for (int ni = 0; ni < 4; ++ni) {
            const int col = wn * 64 + ni * 16 + l15;
#pragma unroll
            for (int j = 0; j < 4; ++j)
                Pb[(row0 + j) * 128 + col] = acc[mi][ni][j];
        }
    }
}

// ---------- reduce partials over chunks -> GB bf16 [4][512][512] ----------
__global__ void k_greduce(const float* __restrict__ P, unsigned* __restrict__ GB2) {
    const long idx = (long)blockIdx.x * 256 + threadIdx.x;
    const int b   = (int)(idx >> 17);
    const int rem = (int)(idx & 131071);
    const int c   = rem >> 8;
    const int cp0 = (rem & 255) * 2;
    const int tp  = (c >> 7) * 4 + (cp0 >> 7);
    const int e   = (c & 127) * 128 + (cp0 & 127);
    const float* Pp = P + ((long)(b * 8) * 16 + tp) * 16384 + e;
    float s0 = 0.f, s1 = 0.f;
#pragma unroll
    for (int ch = 0; ch < 8; ++ch) {
        const float2 v = *(const float2*)(Pp + (long)ch * 16 * 16384);
        s0 += v.x; s1 += v.y;
    }
    GB2[idx] = (unsigned)f2bf(s0) | ((unsigned)f2bf(s1) << 16);
}

// ---------- row-dots for sumsq ----------
__global__ void k_ssq(const unsigned short* __restrict__ WCT, const unsigned short* __restrict__ T1e,
                      const unsigned short* __restrict__ T2e, float* __restrict__ SSQ) {
    const int b = blockIdx.y;
    const int o = blockIdx.x * 256 + threadIdx.x;
    const unsigned short* wrow;
    const unsigned short* trow;
    if (o < 512) {
        wrow = WCT + (long)o * 512;
        trow = T1e + (long)b * 262144 + (long)o * 512;
    } else {
        const int d = o - 512;
        wrow = WCT + 262144 + (long)d * 512;
        trow = T2e + (long)b * 262144 + (long)d * 512;
    }
    float s = 0.f;
    for (int c = 0; c < 512; c += 8) {
        const s16x8 w = *(const s16x8*)&wrow[c];
        const s16x8 v = *(const s16x8*)&trow[c];
#pragma unroll
        for (int j = 0; j < 8; ++j)
            s += bf2f((unsigned short)w[j]) * bf2f((unsigned short)v[j]);
    }
    SSQ[b * 1024 + o] = s;
}

// ---------- softmax -> block-diagonal bf16 matrix MBD[b][h*64+e][h*64+d] ----------
// One block per (b,h); wave handles 16 d-rows; LDS transpose; coalesced 32B stores.
__global__ __launch_bounds__(256)
void k_softmax_bd(const float* __restrict__ attn, const float* __restrict__ sumsq,
                  const float* __restrict__ rescale, unsigned short* __restrict__ MBD) {
    __shared__ unsigned short TD[64 * 68];
    const int bh = blockIdx.x;
    const int b = bh >> 3, h = bh & 7;
    const int wave = threadIdx.x >> 6, e = threadIdx.x & 63;
    const float rs   = rescale[h];
    const float invq = rsqrtf(sumsq[b * 1024 + h * 64 + e]);
#pragma unroll 4
    for (int i = 0; i < 16; ++i) {
        const int d = wave * 16 + i;
        const float invk = rsqrtf(sumsq[b * 1024 + 512 + h * 64 + d]);
        const float v = attn[((long)b * 512 + h * 64 + d) * 512 + h * 64 + e] * invk * invq * rs;
        float mx = v;
#pragma unroll
        for (int off = 32; off >= 1; off >>= 1) mx = fmaxf(mx, __shfl_xor(mx, off));
        const float l = __expf(v - mx);
        float s = l;
#pragma unroll
        for (int off = 32; off >= 1; off >>= 1) s += __shfl_xor(s, off);
        TD[e * 68 + d] = f2bf(l / s);
    }
    __syncthreads();
    const int er = threadIdx.x >> 2, dc = (threadIdx.x & 3) * 16;
    union { unsigned short h[16]; uint4 u[2]; } pk;
#pragma unroll
    for (int j = 0; j < 16; ++j) pk.h[j] = TD[er * 68 + dc + j];
    uint4* dst = (uint4*)(MBD + ((long)b * 512 + h * 64 + er) * 512 + h * 64 + dc);
    dst[0] = pk.u[0];
    dst[1] = pk.u[1];
}

// ---------- depthwise 3x3 conv, x-unrolled x4, fast GELU ----------
__global__ __launch_bounds__(256)
void k_conv1_gelu(const unsigned short* __restrict__ V,
                  const float* __restrict__ w, unsigned short* __restrict__ g) {
    const int x0 = blockIdx.x * 16;
    const int y  = blockIdx.y;
    const int b  = blockIdx.z;
    const int c0 = threadIdx.x * 2;
    float wq0[9], wq1[9];
#pragma unroll
    for (int i = 0; i < 9; ++i) { wq0[i] = w[c0 * 9 + i]; wq1[i] = w[(c0 + 1) * 9 + i]; }
    const long pixbase = (long)b * 16384;

    auto ld = [&](int yy, int xx) -> float2 {
        if (yy < 0 || yy > 127 || xx < 0 || xx > 127) return make_float2(0.f, 0.f);
        return bfpair(*(const unsigned*)(V + (pixbase + (long)yy * 128 + xx) * 512 + c0));
    };

    float2 col[3][6];
#pragma unroll
    for (int ky = 0; ky < 3; ++ky) {
        col[ky][0] = ld(y + ky - 1, x0 - 1);
        col[ky][1] = ld(y + ky - 1, x0);
    }
    for (int xq = 0; xq < 4; ++xq) {
        const int xb = x0 + xq * 4;
#pragma unroll
        for (int ky = 0; ky < 3; ++ky)
#pragma unroll
            for (int j = 0; j < 4; ++j)
                col[ky][2 + j] = ld(y + ky - 1, xb + 1 + j);
#pragma unroll
        for (int j = 0; j < 4; ++j) {
            float a0 = 0.f, a1 = 0.f;
#pragma unroll
            for (int ky = 0; ky < 3; ++ky)
#pragma unroll
                for (int kx = 0; kx < 3; ++kx) {
                    a0 += col[ky][j + kx].x * wq0[ky * 3 + kx];
                    a1 += col[ky][j + kx].y * wq1[ky * 3 + kx];
                }
            a0 = gelu_tanh(a0);
            a1 = gelu_tanh(a1);
            const unsigned up = (unsigned)f2bf(a0) | ((unsigned)f2bf(a1) << 16);
            *(unsigned*)(g + (pixbase + (long)y * 128 + xb + j) * 512 + c0) = up;
        }
#pragma unroll
        for (int ky = 0; ky < 3; ++ky) {
            col[ky][0] = col[ky][4];
            col[ky][1] = col[ky][5];
        }
    }
}

// conv2: bf16 in -> bf16 out (no RMW; added in out-proj epilogue)
__global__ __launch_bounds__(256)
void k_conv2_bf(const unsigned short* __restrict__ gin,
                const float* __restrict__ w, unsigned short* __restrict__ outbf) {
    const int x0 = blockIdx.x * 16;
    const int y  = blockIdx.y;
    const int b  = blockIdx.z;
    const int c0 = threadIdx.x * 2;
    float wq0[9], wq1[9];
#pragma unroll
    for (int i = 0; i < 9; ++i) { wq0[i] = w[c0 * 9 + i]; wq1[i] = w[(c0 + 1) * 9 + i]; }
    const long pixbase = (long)b * 16384;

    auto ld = [&](int yy, int xx) -> float2 {
        if (yy < 0 || yy > 127 || xx < 0 || xx > 127) return make_float2(0.f, 0.f);
        return bfpair(*(const unsigned*)(gin + (pixbase + (long)yy * 128 + xx) * 512 + c0));
    };

    float2 col[3][6];
#pragma unroll
    for (int ky = 0; ky < 3; ++ky) {
        col[ky][0] = ld(y + ky - 1, x0 - 1);
        col[ky][1] = ld(y + ky - 1, x0);
    }
    for (int xq = 0; xq < 4; ++xq) {
        const int xb = x0 + xq * 4;
#pragma unroll
        for (int ky = 0; ky < 3; ++ky)
#pragma unroll
            for (int j = 0; j < 4; ++j)
                col[ky][2 + j] = ld(y + ky - 1, xb + 1 + j);
#pragma unroll
        for (int j = 0; j < 4; ++j) {
            float a0 = 0.f, a1 = 0.f;
#pragma unroll
            for (int ky = 0; ky < 3; ++ky)
#pragma unroll
                for (int kx = 0; kx < 3; ++kx) {
                    a0 += col[ky][j + kx].x * wq0[ky * 3 + kx];
                    a1 += col[ky][j + kx].y * wq1[ky * 3 + kx];
                }
            const unsigned up = (unsigned)f2bf(a0) | ((unsigned)f2bf(a1) << 16);
            *(unsigned*)(outbf + (pixbase + (long)y * 128 + xb + j) * 512 + c0) = up;
        }
#pragma unroll
        for (int ky = 0; ky < 3; ++ky) {
            col[ky][0] = col[ky][4];
            col[ky][1] = col[ky][5];
        }
    }
}

// ---------- launch ----------
extern "C" void kernel_launch(void* const* d_in, const int* in_sizes, int n_in,
                              void* d_out, int out_size, void* d_ws, size_t ws_size,
                              hipStream_t stream) {
    const float* x_in    = (const float*)d_in[0];
    const float* Wq      = (const float*)d_in[1];
    const float* Wk      = (const float*)d_in[2];
    const float* Wv      = (const float*)d_in[3];
    const float* rescale = (const float*)d_in[4];
    const float* Wp      = (const float*)d_in[5];
    const float* bp      = (const float*)d_in[6];
    const float* c1w     = (const float*)d_in[7];
    const float* c2w     = (const float*)d_in[8];
    float* out = (float*)d_out;

    char* ws = (char*)d_ws;
    unsigned short* XBF = (unsigned short*)(ws);                  // [65536][512] bf16; reused as gelu buf
    unsigned short* VBF = (unsigned short*)(ws + 67108864LL);     // [65536][512] bf16
    unsigned short* XT  = (unsigned short*)(ws + 134217728LL);    // [4][512][16384] bf16; reused as CV2
    unsigned short* CV2 = XT;                                     // conv2 out bf16 (after gram done)
    float*          P   = (float*)(ws + 201326592LL);             // [4][8][16][16384] f32 partials
    unsigned short* WCT = (unsigned short*)(ws + 234881024LL);    // [WqT;WkT;WvT;WpT] [2048][512] bf16
    unsigned short* GB  = (unsigned short*)(ws + 236978176LL);    // [4][512][512] bf16
    unsigned short* T1e = (unsigned short*)(ws + 239075328LL);    // Wq^T G
    unsigned short* T2e = (unsigned short*)(ws + 241172480LL);    // Wk^T G
    float*          SSQ = (float*)(ws + 243269632LL);             // [4][1024]
    float*          ATTF= (float*)(ws + 243286016LL);             // [4][512][512] f32
    unsigned short* MBD = (unsigned short*)(ws + 247480320LL);    // blockdiag probs [4][512][512] bf16
    unsigned short* WEF = (unsigned short*)(ws + 249577472LL);    // WeffT [4][512][512] bf16

    (void)hipMemsetAsync(MBD, 0, 2097152, stream);

    k_cvt_tr<<<dim3(8, 1024), dim3(256), 0, stream>>>(x_in, XBF, XT);
    k_build_wcat<<<dim3(16, 64), dim3(256), 0, stream>>>(Wq, Wk, Wv, Wp, WCT);

    // V = X @ Wv
    gemm_mfma<1, 0, 0><<<dim3(4, 512, 1), dim3(256), 0, stream>>>(
        XBF, WCT + 2 * 262144, (void*)VBF, nullptr, nullptr, 512, 512, 512, 512, 0L, 0L, 0L);

    // Gram matrix (uses XT, must finish before conv2 overwrites it)
    gemm_gram<<<dim3(4, 4, 32), dim3(256), 0, stream>>>(XT, P);
    k_greduce<<<dim3(2048), dim3(256), 0, stream>>>(P, (unsigned*)GB);

    // sandwiches
    gemm_mfma<1, 0, 0><<<dim3(4, 4, 4), dim3(256), 0, stream>>>(
        WCT + 262144, GB, (void*)T2e, nullptr, nullptr, 512, 512, 512, 512, 0L, 262144L, 262144L);
    gemm_mfma<1, 0, 0><<<dim3(4, 4, 4), dim3(256), 0, stream>>>(
        WCT, GB, (void*)T1e, nullptr, nullptr, 512, 512, 512, 512, 0L, 262144L, 262144L);
    gemm_mfma<0, 0, 0><<<dim3(4, 4, 4), dim3(256), 0, stream>>>(
        T2e, WCT, (void*)ATTF, nullptr, nullptr, 512, 512, 512, 512, 262144L, 0L, 262144L);

    k_ssq<<<dim3(4, 4), dim3(256), 0, stream>>>(WCT, T1e, T2e, SSQ);
    k_softmax_bd<<<dim3(32), dim3(256), 0, stream>>>(ATTF, SSQ, rescale, MBD);

    // Weff^T[b] = WpT x MBD[b]^T  (replaces serial k_weff)
    gemm_mfma<1, 0, 0><<<dim3(4, 4, 4), dim3(256), 0, stream>>>(
        WCT + 3 * 262144, MBD, (void*)WEF, nullptr, nullptr, 512, 512, 512, 512, 0L, 262144L, 262144L);

    // positional branch first: conv1 -> conv2 into CV2 (bf16)
    k_conv1_gelu<<<dim3(8, 128, 4), dim3(256), 0, stream>>>(VBF, c1w, XBF);
    k_conv2_bf<<<dim3(8, 128, 4), dim3(256), 0, stream>>>(XBF, c2w, CV2);

    // out = V @ Weff^T + bp + CV2
    gemm_mfma<0, 1, 1><<<dim3(4, 128, 4), dim3(256), 0, stream>>>(
        VBF, WEF, (void*)out, bp, CV2, 512, 512, 512, 512,
        (long)16384 * 512, 262144L, (long)16384 * 512);
}